// Round 4
// baseline (163.271 us; speedup 1.0000x reference)
//
#include <hip/hip_runtime.h>
#include <hip/hip_bf16.h>

// GAT layer, N=4096, FIN=512, H=4 heads, F=64.
// R4: occupancy fix for K3 — j split 4->8 strips (grid 128x8=1024 blocks,
// 4 blocks/CU, 16 waves/CU; R3 was 2 blocks/CU and latency-bound:
// MfmaUtil 11 / VALUBusy 33 / Occ 21, all low). Numerics unchanged.
//   K1: XW = X @ W (f32 tiled GEMM)
//   K2: f1h/f2h score projections x log2e [H][N]; bf16-split transpose V{hi,lo}
//   K3: waves = heads (disjoint writes); P built in MFMA A-fragment layout;
//       split-precision PV (hi*hi+hi*lo+lo*hi) + ones-rowsum MFMAs.
//       No max-subtraction (scores bounded -> softmax exact without it).
//   K4: combine njb j-partials, normalize, ELU.
// ws: pacc njb*4MB (XW aliases first 4MB) | f1h | f2h | Vhi | Vlo | plsum.
// njb = 8 if ws fits else 4 (pure function of ws_size -> deterministic).

#define NN   4096
#define FIN  512
#define H    4
#define F    64
#define HF   256
#define LOG2E 1.44269504088896340736f

typedef __attribute__((ext_vector_type(4))) float f32x4;
typedef __attribute__((ext_vector_type(8))) short short8;

// ---------------- K1: GEMM (f32) ----------------
#define TM 64
#define TN 64
#define TK 16

__global__ __launch_bounds__(256) void gemm_xw(const float* __restrict__ X,
                                               const float* __restrict__ W,
                                               float* __restrict__ XW) {
    __shared__ float Ast[TK][TM];
    __shared__ float Bs[TK][TN];
    const int bi = blockIdx.x;
    const int bj = blockIdx.y;
    const int t  = threadIdx.x;
    const int tx = t & 15, ty = t >> 4;

    float acc[4][4];
#pragma unroll
    for (int a = 0; a < 4; ++a)
#pragma unroll
        for (int b = 0; b < 4; ++b) acc[a][b] = 0.f;

    const int ar = t >> 2, ac4 = (t & 3) * 4;
    const int bk = t >> 4, bn4 = (t & 15) * 4;

    const float* Arow = X + (bi * TM + ar) * FIN + ac4;
    const float* Brow = W + bk * HF + bj * TN + bn4;

    for (int k0 = 0; k0 < FIN; k0 += TK) {
        float4 av = *(const float4*)(Arow + k0);
        float4 bv = *(const float4*)(Brow + k0 * HF);
        __syncthreads();
        Ast[ac4 + 0][ar] = av.x;
        Ast[ac4 + 1][ar] = av.y;
        Ast[ac4 + 2][ar] = av.z;
        Ast[ac4 + 3][ar] = av.w;
        *(float4*)&Bs[bk][bn4] = bv;
        __syncthreads();
#pragma unroll
        for (int k = 0; k < TK; ++k) {
            float4 a4 = *(const float4*)&Ast[k][ty * 4];
            float4 b4 = *(const float4*)&Bs[k][tx * 4];
            acc[0][0] += a4.x * b4.x; acc[0][1] += a4.x * b4.y;
            acc[0][2] += a4.x * b4.z; acc[0][3] += a4.x * b4.w;
            acc[1][0] += a4.y * b4.x; acc[1][1] += a4.y * b4.y;
            acc[1][2] += a4.y * b4.z; acc[1][3] += a4.y * b4.w;
            acc[2][0] += a4.z * b4.x; acc[2][1] += a4.z * b4.y;
            acc[2][2] += a4.z * b4.z; acc[2][3] += a4.z * b4.w;
            acc[3][0] += a4.w * b4.x; acc[3][1] += a4.w * b4.y;
            acc[3][2] += a4.w * b4.z; acc[3][3] += a4.w * b4.w;
        }
    }
#pragma unroll
    for (int r = 0; r < 4; ++r) {
        float4 o = make_float4(acc[r][0], acc[r][1], acc[r][2], acc[r][3]);
        *(float4*)&XW[(bi * TM + ty * 4 + r) * HF + bj * TN + tx * 4] = o;
    }
}

// ---------------- K2: scores (x log2e, [H][N]) + bf16-split transpose --------
__global__ __launch_bounds__(256) void scores_transpose(
        const float* __restrict__ XW, const float* __restrict__ a_src,
        const float* __restrict__ a_dst, float* __restrict__ f1h,
        float* __restrict__ f2h, __hip_bfloat16* __restrict__ Vhi,
        __hip_bfloat16* __restrict__ Vlo) {
    const int n = blockIdx.x * 64 + (threadIdx.x & 63);
    const int h = threadIdx.x >> 6;
    const float* row = XW + (size_t)n * HF + h * F;

    float v[F];
#pragma unroll
    for (int k4 = 0; k4 < 16; ++k4) {
        float4 x = *(const float4*)(row + k4 * 4);
        v[k4 * 4 + 0] = x.x; v[k4 * 4 + 1] = x.y;
        v[k4 * 4 + 2] = x.z; v[k4 * 4 + 3] = x.w;
    }
    const float* as = a_src + h * F;   // wave-uniform -> scalar loads
    const float* ad = a_dst + h * F;
    float s1 = 0.f, s2 = 0.f;
#pragma unroll
    for (int k = 0; k < F; ++k) { s1 += v[k] * as[k]; s2 += v[k] * ad[k]; }
    f1h[h * NN + n] = s1 * LOG2E;
    f2h[h * NN + n] = s2 * LOG2E;

    // bf16-split transposed copy: V{hi,lo}[h*F+k][n] (coalesced 2B over n)
#pragma unroll
    for (int k = 0; k < F; ++k) {
        __hip_bfloat16 hb = __float2bfloat16(v[k]);
        float hf_ = __bfloat162float(hb);
        __hip_bfloat16 lb = __float2bfloat16(v[k] - hf_);
        Vhi[(size_t)(h * F + k) * NN + n] = hb;
        Vlo[(size_t)(h * F + k) * NN + n] = lb;
    }
}

// ---------------- K3: MFMA fused attention (partials) ----------------
// grid (128, njb): ib = 32-row block, jb owns j in [jb*jlen, jb*jlen+jlen).
// wave w = head w; all waves same j range -> disjoint output columns.
__global__ __launch_bounds__(256) void gat_attn_mfma(
        const int* __restrict__ A, const __hip_bfloat16* __restrict__ Vhi,
        const __hip_bfloat16* __restrict__ Vlo,
        const float* __restrict__ f1h, const float* __restrict__ f2h,
        float* __restrict__ pacc, float* __restrict__ plsum, int jlen) {
    const int ib = blockIdx.x, jb = blockIdx.y;
    const int h    = threadIdx.x >> 6;
    const int lane = threadIdx.x & 63;
    const int il = lane & 15;        // MFMA row (A) / col (B, C/D)
    const int kg = lane >> 4;        // k-group
    const int i0 = ib * 32 + il;     // rowtile 0
    const int i1 = i0 + 16;          // rowtile 1

    const float c0 = f1h[h * NN + i0];
    const float c1 = f1h[h * NN + i1];

    f32x4 acc0[4], acc1[4], lac0, lac1;
#pragma unroll
    for (int ft = 0; ft < 4; ++ft) {
        acc0[ft] = (f32x4){0.f, 0.f, 0.f, 0.f};
        acc1[ft] = (f32x4){0.f, 0.f, 0.f, 0.f};
    }
    lac0 = (f32x4){0.f, 0.f, 0.f, 0.f};
    lac1 = (f32x4){0.f, 0.f, 0.f, 0.f};

    short8 ones;
#pragma unroll
    for (int e = 0; e < 8; ++e) ones[e] = (short)0x3F80;   // bf16 1.0

    const int ncc = jlen >> 5;
    for (int cc = 0; cc < ncc; ++cc) {
        const int jl = jb * jlen + cc * 32 + kg * 8;   // this lane's 8 k's

        const int4* ap0 = (const int4*)(A + (size_t)i0 * NN + jl);
        const int4* ap1 = (const int4*)(A + (size_t)i1 * NN + jl);
        int4 a00 = ap0[0], a01 = ap0[1];
        int4 a10 = ap1[0], a11 = ap1[1];
        int av0[8] = {a00.x, a00.y, a00.z, a00.w, a01.x, a01.y, a01.z, a01.w};
        int av1[8] = {a10.x, a10.y, a10.z, a10.w, a11.x, a11.y, a11.z, a11.w};

        float4 g0 = *(const float4*)(f2h + (size_t)h * NN + jl);
        float4 g1 = *(const float4*)(f2h + (size_t)h * NN + jl + 4);
        float gv[8] = {g0.x, g0.y, g0.z, g0.w, g1.x, g1.y, g1.z, g1.w};

        short8 p0h, p0l, p1h, p1l;
#pragma unroll
        for (int e = 0; e < 8; ++e) {
            float s0 = c0 + gv[e];
            s0 = fmaxf(s0, 0.2f * s0);            // leaky relu (x log2e commutes)
            float p0 = exp2f(s0);                 // no max-sub: bounded
            p0 = (av0[e] != 0) ? p0 : 0.f;
            __hip_bfloat16 h0 = __float2bfloat16(p0);
            __hip_bfloat16 l0 = __float2bfloat16(p0 - __bfloat162float(h0));
            p0h[e] = __builtin_bit_cast(short, h0);
            p0l[e] = __builtin_bit_cast(short, l0);

            float s1 = c1 + gv[e];
            s1 = fmaxf(s1, 0.2f * s1);
            float p1 = exp2f(s1);
            p1 = (av1[e] != 0) ? p1 : 0.f;
            __hip_bfloat16 h1 = __float2bfloat16(p1);
            __hip_bfloat16 l1 = __float2bfloat16(p1 - __bfloat162float(h1));
            p1h[e] = __builtin_bit_cast(short, h1);
            p1l[e] = __builtin_bit_cast(short, l1);
        }

#pragma unroll
        for (int ft = 0; ft < 4; ++ft) {
            const size_t boff = (size_t)(h * F + ft * 16 + il) * NN + jl;
            short8 bh = *reinterpret_cast<const short8*>(Vhi + boff);
            short8 bl = *reinterpret_cast<const short8*>(Vlo + boff);
            acc0[ft] = __builtin_amdgcn_mfma_f32_16x16x32_bf16(p0h, bh, acc0[ft], 0, 0, 0);
            acc0[ft] = __builtin_amdgcn_mfma_f32_16x16x32_bf16(p0h, bl, acc0[ft], 0, 0, 0);
            acc0[ft] = __builtin_amdgcn_mfma_f32_16x16x32_bf16(p0l, bh, acc0[ft], 0, 0, 0);
            acc1[ft] = __builtin_amdgcn_mfma_f32_16x16x32_bf16(p1h, bh, acc1[ft], 0, 0, 0);
            acc1[ft] = __builtin_amdgcn_mfma_f32_16x16x32_bf16(p1h, bl, acc1[ft], 0, 0, 0);
            acc1[ft] = __builtin_amdgcn_mfma_f32_16x16x32_bf16(p1l, bh, acc1[ft], 0, 0, 0);
        }
        lac0 = __builtin_amdgcn_mfma_f32_16x16x32_bf16(p0h, ones, lac0, 0, 0, 0);
        lac0 = __builtin_amdgcn_mfma_f32_16x16x32_bf16(p0l, ones, lac0, 0, 0, 0);
        lac1 = __builtin_amdgcn_mfma_f32_16x16x32_bf16(p1h, ones, lac1, 0, 0, 0);
        lac1 = __builtin_amdgcn_mfma_f32_16x16x32_bf16(p1l, ones, lac1, 0, 0, 0);
    }

    // C/D layout: col = lane&15, row = (lane>>4)*4 + reg
    float* pb = pacc + (size_t)jb * NN * HF + (size_t)(ib * 32) * HF;
#pragma unroll
    for (int ft = 0; ft < 4; ++ft)
#pragma unroll
        for (int r = 0; r < 4; ++r) {
            pb[(kg * 4 + r) * HF + h * F + ft * 16 + il]        = acc0[ft][r];
            pb[(16 + kg * 4 + r) * HF + h * F + ft * 16 + il]   = acc1[ft][r];
        }

    if (il == 0) {   // ones-MFMA: every col holds the row sum; use col 0
#pragma unroll
        for (int r = 0; r < 4; ++r) {
            plsum[(size_t)jb * NN * H + (size_t)(ib * 32 + kg * 4 + r) * H + h]      = lac0[r];
            plsum[(size_t)jb * NN * H + (size_t)(ib * 32 + 16 + kg * 4 + r) * H + h] = lac1[r];
        }
    }
}

// ---------------- K4: combine partials, normalize, ELU ----------------
__global__ __launch_bounds__(256) void finalize(
        const float* __restrict__ pacc, const float* __restrict__ plsum,
        const __hip_bfloat16* __restrict__ Vhi,
        const __hip_bfloat16* __restrict__ Vlo, float* __restrict__ out,
        int njb) {
    const int gid = blockIdx.x * 256 + threadIdx.x;   // 0 .. NN*HF-1
    const int i = gid >> 8, hf = gid & 255, h = hf >> 6;
    float a = 0.f, l = 0.f;
    for (int jb = 0; jb < njb; ++jb) {
        a += pacc[(size_t)jb * NN * HF + gid];
        l += plsum[(size_t)jb * NN * H + (size_t)i * H + h];
    }
    if (l == 0.f) {   // empty row: reference softmax degenerates to uniform
        float s = 0.f;
        const __hip_bfloat16* ch = Vhi + (size_t)hf * NN;
        const __hip_bfloat16* cl = Vlo + (size_t)hf * NN;
        for (int j = 0; j < NN; ++j)
            s += __bfloat162float(ch[j]) + __bfloat162float(cl[j]);
        a = s; l = (float)NN;
    }
    float o = a / l;
    out[gid] = (o > 0.f) ? o : (exp2f(o * LOG2E) - 1.f);
}

// ---------------- launch ----------------
extern "C" void kernel_launch(void* const* d_in, const int* in_sizes, int n_in,
                              void* d_out, int out_size, void* d_ws, size_t ws_size,
                              hipStream_t stream) {
    const float* X     = (const float*)d_in[0];
    const int*   A     = (const int*)d_in[1];
    const float* W     = (const float*)d_in[2];
    const float* a_src = (const float*)d_in[3];
    const float* a_dst = (const float*)d_in[4];
    float* out = (float*)d_out;

    // njb strips of jlen = NN/njb. ws need (bytes):
    //   pacc njb*NN*HF*4 | f1h,f2h 2*NN*H*4 | Vhi,Vlo 2*HF*NN*2 | plsum njb*NN*H*4
    const size_t fixed = (size_t)2 * NN * H * 4 + (size_t)2 * HF * NN * 2;
    auto need = [&](int njb) {
        return (size_t)njb * NN * HF * 4 + fixed + (size_t)njb * NN * H * 4;
    };
    const int njb = (ws_size >= need(8)) ? 8 : 4;   // deterministic in ws_size
    const int jlen = NN / njb;

    float* pacc = (float*)d_ws;
    float* XW   = (float*)d_ws;                 // alias, dead after K2
    float* f1h  = pacc + (size_t)njb * NN * HF;
    float* f2h  = f1h + (size_t)NN * H;
    __hip_bfloat16* Vhi = (__hip_bfloat16*)(f2h + (size_t)NN * H);
    __hip_bfloat16* Vlo = Vhi + (size_t)HF * NN;
    float* plsum = (float*)(Vlo + (size_t)HF * NN);

    gemm_xw<<<dim3(64, 4), 256, 0, stream>>>(X, W, XW);
    scores_transpose<<<64, 256, 0, stream>>>(XW, a_src, a_dst, f1h, f2h, Vhi, Vlo);
    gat_attn_mfma<<<dim3(128, njb), 256, 0, stream>>>(A, Vhi, Vlo, f1h, f2h, pacc, plsum, jlen);
    finalize<<<NN * HF / 256, 256, 0, stream>>>(pacc, plsum, Vhi, Vlo, out, njb);
}

// Round 5
// 136.729 us; speedup vs baseline: 1.1941x; 1.1941x over previous
//
#include <hip/hip_runtime.h>
#include <hip/hip_bf16.h>

// GAT layer, N=4096, FIN=512, H=4 heads, F=64.
// R5: K3 was A-pattern-bound (64MB int32 read at ~600GB/s effective = 105us).
//   - pack_mask: A -> 2MB bitmask via __ballot (coalesced 64MB stream read)
//   - K3 reads 1 broadcast dword of mask bits per cc (L1-hit), compile-time
//     trip counts (R4's runtime bounds killed unrolling), truncation-based
//     bf16 split of P packed with v_perm (exact lo, ~3 VALU/elem vs ~8).
//   K1: XW = X @ W (f32 tiled GEMM)       K2: scores + bf16-split V transpose
//   K3: waves=heads, 32 rows/block, split-precision PV + ones-rowsum MFMAs,
//       no max-subtraction (scores bounded -> softmax exact without it)
//   K4: combine njb j-partials, normalize, ELU.
// ws: pacc njb*4MB (XW aliases first 4MB) | f1h | f2h | Vhi | Vlo | plsum | Ab
// njb = 8 if ws fits else 4 (pure function of ws_size -> deterministic).

#define NN   4096
#define FIN  512
#define H    4
#define F    64
#define HF   256
#define LOG2E 1.44269504088896340736f

typedef __attribute__((ext_vector_type(4))) float f32x4;
typedef __attribute__((ext_vector_type(8))) short short8;

union U8 { short8 s; unsigned int w[4]; };

// ---------------- K0: bit-pack adjacency ----------------
// chunk c = 64 consecutive ints of A; wave ballots a!=0 -> u64 mask.
__global__ __launch_bounds__(256) void pack_mask(const int* __restrict__ A,
                                                 unsigned long long* __restrict__ Ab) {
    const int gw   = (blockIdx.x * 256 + threadIdx.x) >> 6;   // global wave id
    const int lane = threadIdx.x & 63;
    const int nchunk = NN * NN / 64;                          // 262144
    for (int c = gw; c < nchunk; c += 8192) {                 // 2048 blk * 4 waves
        int a = A[(size_t)c * 64 + lane];
        unsigned long long m = __ballot(a != 0);
        if (lane == 0) Ab[c] = m;
    }
}

// ---------------- K1: GEMM (f32) ----------------
#define TM 64
#define TN 64
#define TK 16

__global__ __launch_bounds__(256) void gemm_xw(const float* __restrict__ X,
                                               const float* __restrict__ W,
                                               float* __restrict__ XW) {
    __shared__ float Ast[TK][TM];
    __shared__ float Bs[TK][TN];
    const int bi = blockIdx.x;
    const int bj = blockIdx.y;
    const int t  = threadIdx.x;
    const int tx = t & 15, ty = t >> 4;

    float acc[4][4];
#pragma unroll
    for (int a = 0; a < 4; ++a)
#pragma unroll
        for (int b = 0; b < 4; ++b) acc[a][b] = 0.f;

    const int ar = t >> 2, ac4 = (t & 3) * 4;
    const int bk = t >> 4, bn4 = (t & 15) * 4;

    const float* Arow = X + (bi * TM + ar) * FIN + ac4;
    const float* Brow = W + bk * HF + bj * TN + bn4;

    for (int k0 = 0; k0 < FIN; k0 += TK) {
        float4 av = *(const float4*)(Arow + k0);
        float4 bv = *(const float4*)(Brow + k0 * HF);
        __syncthreads();
        Ast[ac4 + 0][ar] = av.x;
        Ast[ac4 + 1][ar] = av.y;
        Ast[ac4 + 2][ar] = av.z;
        Ast[ac4 + 3][ar] = av.w;
        *(float4*)&Bs[bk][bn4] = bv;
        __syncthreads();
#pragma unroll
        for (int k = 0; k < TK; ++k) {
            float4 a4 = *(const float4*)&Ast[k][ty * 4];
            float4 b4 = *(const float4*)&Bs[k][tx * 4];
            acc[0][0] += a4.x * b4.x; acc[0][1] += a4.x * b4.y;
            acc[0][2] += a4.x * b4.z; acc[0][3] += a4.x * b4.w;
            acc[1][0] += a4.y * b4.x; acc[1][1] += a4.y * b4.y;
            acc[1][2] += a4.y * b4.z; acc[1][3] += a4.y * b4.w;
            acc[2][0] += a4.z * b4.x; acc[2][1] += a4.z * b4.y;
            acc[2][2] += a4.z * b4.z; acc[2][3] += a4.z * b4.w;
            acc[3][0] += a4.w * b4.x; acc[3][1] += a4.w * b4.y;
            acc[3][2] += a4.w * b4.z; acc[3][3] += a4.w * b4.w;
        }
    }
#pragma unroll
    for (int r = 0; r < 4; ++r) {
        float4 o = make_float4(acc[r][0], acc[r][1], acc[r][2], acc[r][3]);
        *(float4*)&XW[(bi * TM + ty * 4 + r) * HF + bj * TN + tx * 4] = o;
    }
}

// ---------------- K2: scores (x log2e, [H][N]) + bf16-split transpose --------
__global__ __launch_bounds__(256) void scores_transpose(
        const float* __restrict__ XW, const float* __restrict__ a_src,
        const float* __restrict__ a_dst, float* __restrict__ f1h,
        float* __restrict__ f2h, __hip_bfloat16* __restrict__ Vhi,
        __hip_bfloat16* __restrict__ Vlo) {
    const int n = blockIdx.x * 64 + (threadIdx.x & 63);
    const int h = threadIdx.x >> 6;
    const float* row = XW + (size_t)n * HF + h * F;

    float v[F];
#pragma unroll
    for (int k4 = 0; k4 < 16; ++k4) {
        float4 x = *(const float4*)(row + k4 * 4);
        v[k4 * 4 + 0] = x.x; v[k4 * 4 + 1] = x.y;
        v[k4 * 4 + 2] = x.z; v[k4 * 4 + 3] = x.w;
    }
    const float* as = a_src + h * F;   // wave-uniform -> scalar loads
    const float* ad = a_dst + h * F;
    float s1 = 0.f, s2 = 0.f;
#pragma unroll
    for (int k = 0; k < F; ++k) { s1 += v[k] * as[k]; s2 += v[k] * ad[k]; }
    f1h[h * NN + n] = s1 * LOG2E;
    f2h[h * NN + n] = s2 * LOG2E;

    // bf16-split transposed copy: V{hi,lo}[h*F+k][n] (coalesced 2B over n)
#pragma unroll
    for (int k = 0; k < F; ++k) {
        __hip_bfloat16 hb = __float2bfloat16(v[k]);
        float hf_ = __bfloat162float(hb);
        __hip_bfloat16 lb = __float2bfloat16(v[k] - hf_);
        Vhi[(size_t)(h * F + k) * NN + n] = hb;
        Vlo[(size_t)(h * F + k) * NN + n] = lb;
    }
}

// ---------------- K3: MFMA fused attention (partials) ----------------
// grid (128, njb): ib = 32-row block, jb owns JLEN cols. wave = head.
template <int JLEN>
__global__ __launch_bounds__(256) void gat_attn_mfma(
        const unsigned int* __restrict__ Ab32,
        const __hip_bfloat16* __restrict__ Vhi,
        const __hip_bfloat16* __restrict__ Vlo,
        const float* __restrict__ f1h, const float* __restrict__ f2h,
        float* __restrict__ pacc, float* __restrict__ plsum) {
    constexpr int NCC = JLEN / 32;
    const int ib = blockIdx.x, jb = blockIdx.y;
    const int h    = threadIdx.x >> 6;
    const int lane = threadIdx.x & 63;
    const int il = lane & 15;        // MFMA row (A) / col (B, C/D)
    const int kg = lane >> 4;        // k-group
    const int sh = kg * 8;           // bit shift for this lane's 8 mask bits
    const int i0 = ib * 32 + il;
    const int i1 = i0 + 16;

    const float c0 = f1h[h * NN + i0];
    const float c1 = f1h[h * NN + i1];

    // mask words: row stride NN/32 = 128 words; word cc of this strip
    const unsigned int* ab0 = Ab32 + (size_t)i0 * (NN / 32) + jb * (JLEN / 32);
    const unsigned int* ab1 = Ab32 + (size_t)i1 * (NN / 32) + jb * (JLEN / 32);
    const float* f2p = f2h + (size_t)h * NN + jb * JLEN;

    f32x4 acc0[4], acc1[4], lac0, lac1;
#pragma unroll
    for (int ft = 0; ft < 4; ++ft) {
        acc0[ft] = (f32x4){0.f, 0.f, 0.f, 0.f};
        acc1[ft] = (f32x4){0.f, 0.f, 0.f, 0.f};
    }
    lac0 = (f32x4){0.f, 0.f, 0.f, 0.f};
    lac1 = (f32x4){0.f, 0.f, 0.f, 0.f};

    short8 ones;
#pragma unroll
    for (int e = 0; e < 8; ++e) ones[e] = (short)0x3F80;   // bf16 1.0

#pragma unroll 2
    for (int cc = 0; cc < NCC; ++cc) {
        const unsigned int m0 = ab0[cc] >> sh;    // L1-resident after cc=0
        const unsigned int m1 = ab1[cc] >> sh;

        float4 ga = *(const float4*)(f2p + cc * 32 + sh);
        float4 gb = *(const float4*)(f2p + cc * 32 + sh + 4);
        float gv[8] = {ga.x, ga.y, ga.z, ga.w, gb.x, gb.y, gb.z, gb.w};

        float p0[8], p1[8];
#pragma unroll
        for (int e = 0; e < 8; ++e) {
            float s0 = c0 + gv[e];
            s0 = fmaxf(s0, 0.2f * s0);            // leaky relu (x log2e commutes)
            float q0 = exp2f(s0);                 // no max-sub: s bounded
            p0[e] = ((m0 >> e) & 1u) ? q0 : 0.f;
            float s1 = c1 + gv[e];
            s1 = fmaxf(s1, 0.2f * s1);
            float q1 = exp2f(s1);
            p1[e] = ((m1 >> e) & 1u) ? q1 : 0.f;
        }

        // truncation split: hi = top16(p) (exact bf16), lo = p - hi (exact),
        // packed pairwise with v_perm (result: low short=elem e, high=e+1)
        U8 h0, l0, h1, l1;
#pragma unroll
        for (int e = 0; e < 8; e += 2) {
            unsigned u0a = __float_as_uint(p0[e]), u0b = __float_as_uint(p0[e + 1]);
            h0.w[e >> 1] = __builtin_amdgcn_perm(u0b, u0a, 0x07060302u);
            float la = p0[e]     - __uint_as_float(u0a & 0xFFFF0000u);
            float lb = p0[e + 1] - __uint_as_float(u0b & 0xFFFF0000u);
            l0.w[e >> 1] = __builtin_amdgcn_perm(__float_as_uint(lb),
                                                 __float_as_uint(la), 0x07060302u);
            unsigned u1a = __float_as_uint(p1[e]), u1b = __float_as_uint(p1[e + 1]);
            h1.w[e >> 1] = __builtin_amdgcn_perm(u1b, u1a, 0x07060302u);
            float lc = p1[e]     - __uint_as_float(u1a & 0xFFFF0000u);
            float ld = p1[e + 1] - __uint_as_float(u1b & 0xFFFF0000u);
            l1.w[e >> 1] = __builtin_amdgcn_perm(__float_as_uint(ld),
                                                 __float_as_uint(lc), 0x07060302u);
        }

        const int jl = jb * JLEN + cc * 32 + sh;
#pragma unroll
        for (int ft = 0; ft < 4; ++ft) {
            const size_t boff = (size_t)(h * F + ft * 16 + il) * NN + jl;
            short8 bh = *reinterpret_cast<const short8*>(Vhi + boff);
            short8 bl = *reinterpret_cast<const short8*>(Vlo + boff);
            acc0[ft] = __builtin_amdgcn_mfma_f32_16x16x32_bf16(h0.s, bh, acc0[ft], 0, 0, 0);
            acc0[ft] = __builtin_amdgcn_mfma_f32_16x16x32_bf16(h0.s, bl, acc0[ft], 0, 0, 0);
            acc0[ft] = __builtin_amdgcn_mfma_f32_16x16x32_bf16(l0.s, bh, acc0[ft], 0, 0, 0);
            acc1[ft] = __builtin_amdgcn_mfma_f32_16x16x32_bf16(h1.s, bh, acc1[ft], 0, 0, 0);
            acc1[ft] = __builtin_amdgcn_mfma_f32_16x16x32_bf16(h1.s, bl, acc1[ft], 0, 0, 0);
            acc1[ft] = __builtin_amdgcn_mfma_f32_16x16x32_bf16(l1.s, bh, acc1[ft], 0, 0, 0);
        }
        lac0 = __builtin_amdgcn_mfma_f32_16x16x32_bf16(h0.s, ones, lac0, 0, 0, 0);
        lac0 = __builtin_amdgcn_mfma_f32_16x16x32_bf16(l0.s, ones, lac0, 0, 0, 0);
        lac1 = __builtin_amdgcn_mfma_f32_16x16x32_bf16(h1.s, ones, lac1, 0, 0, 0);
        lac1 = __builtin_amdgcn_mfma_f32_16x16x32_bf16(l1.s, ones, lac1, 0, 0, 0);
    }

    // C/D layout: col = lane&15, row = (lane>>4)*4 + reg
    float* pb = pacc + (size_t)jb * NN * HF + (size_t)(ib * 32) * HF;
#pragma unroll
    for (int ft = 0; ft < 4; ++ft)
#pragma unroll
        for (int r = 0; r < 4; ++r) {
            pb[(kg * 4 + r) * HF + h * F + ft * 16 + il]      = acc0[ft][r];
            pb[(16 + kg * 4 + r) * HF + h * F + ft * 16 + il] = acc1[ft][r];
        }

    if (il == 0) {   // ones-MFMA: every col holds the row sum; use col 0
#pragma unroll
        for (int r = 0; r < 4; ++r) {
            plsum[(size_t)jb * NN * H + (size_t)(ib * 32 + kg * 4 + r) * H + h]      = lac0[r];
            plsum[(size_t)jb * NN * H + (size_t)(ib * 32 + 16 + kg * 4 + r) * H + h] = lac1[r];
        }
    }
}

// ---------------- K4: combine partials, normalize, ELU ----------------
__global__ __launch_bounds__(256) void finalize(
        const float* __restrict__ pacc, const float* __restrict__ plsum,
        const __hip_bfloat16* __restrict__ Vhi,
        const __hip_bfloat16* __restrict__ Vlo, float* __restrict__ out,
        int njb) {
    const int gid = blockIdx.x * 256 + threadIdx.x;   // 0 .. NN*HF-1
    const int i = gid >> 8, hf = gid & 255, h = hf >> 6;
    float a = 0.f, l = 0.f;
    for (int jb = 0; jb < njb; ++jb) {
        a += pacc[(size_t)jb * NN * HF + gid];
        l += plsum[(size_t)jb * NN * H + (size_t)i * H + h];
    }
    if (l == 0.f) {   // empty row: reference softmax degenerates to uniform
        float s = 0.f;
        const __hip_bfloat16* ch = Vhi + (size_t)hf * NN;
        const __hip_bfloat16* cl = Vlo + (size_t)hf * NN;
        for (int j = 0; j < NN; ++j)
            s += __bfloat162float(ch[j]) + __bfloat162float(cl[j]);
        a = s; l = (float)NN;
    }
    float o = a / l;
    out[gid] = (o > 0.f) ? o : (exp2f(o * LOG2E) - 1.f);
}

// ---------------- launch ----------------
extern "C" void kernel_launch(void* const* d_in, const int* in_sizes, int n_in,
                              void* d_out, int out_size, void* d_ws, size_t ws_size,
                              hipStream_t stream) {
    const float* X     = (const float*)d_in[0];
    const int*   A     = (const int*)d_in[1];
    const float* W     = (const float*)d_in[2];
    const float* a_src = (const float*)d_in[3];
    const float* a_dst = (const float*)d_in[4];
    float* out = (float*)d_out;

    // ws need: pacc njb*NN*HF*4 | f 2*NN*H*4 | V 2*HF*NN*2 | plsum njb*NN*H*4
    //          | Ab NN*NN/8
    const size_t fixed = (size_t)2 * NN * H * 4 + (size_t)2 * HF * NN * 2
                       + (size_t)NN * NN / 8;
    auto need = [&](int njb) {
        return (size_t)njb * NN * HF * 4 + (size_t)njb * NN * H * 4 + fixed;
    };
    const int njb = (ws_size >= need(8)) ? 8 : 4;   // deterministic in ws_size

    float* pacc = (float*)d_ws;
    float* XW   = (float*)d_ws;                 // alias, dead after K2
    float* f1h  = pacc + (size_t)njb * NN * HF;
    float* f2h  = f1h + (size_t)NN * H;
    __hip_bfloat16* Vhi = (__hip_bfloat16*)(f2h + (size_t)NN * H);
    __hip_bfloat16* Vlo = Vhi + (size_t)HF * NN;
    float* plsum = (float*)(Vlo + (size_t)HF * NN);
    unsigned long long* Ab = (unsigned long long*)(plsum + (size_t)njb * NN * H);

    pack_mask<<<2048, 256, 0, stream>>>(A, Ab);
    gemm_xw<<<dim3(64, 4), 256, 0, stream>>>(X, W, XW);
    scores_transpose<<<64, 256, 0, stream>>>(XW, a_src, a_dst, f1h, f2h, Vhi, Vlo);
    if (njb == 8)
        gat_attn_mfma<512><<<dim3(128, 8), 256, 0, stream>>>(
            (const unsigned int*)Ab, Vhi, Vlo, f1h, f2h, pacc, plsum);
    else
        gat_attn_mfma<1024><<<dim3(128, 4), 256, 0, stream>>>(
            (const unsigned int*)Ab, Vhi, Vlo, f1h, f2h, pacc, plsum);
    finalize<<<NN * HF / 256, 256, 0, stream>>>(pacc, plsum, Vhi, Vlo, out, njb);
}

// Round 6
// 118.391 us; speedup vs baseline: 1.3791x; 1.1549x over previous
//
#include <hip/hip_runtime.h>
#include <hip/hip_bf16.h>

// GAT layer, N=4096, FIN=512, H=4 heads, F=64.
// R6: structural fusion + latency attack.
//   K1: fused GEMM+scores+transpose. Block = 32 rows x 1 head (TN=64=F).
//       XW tile stays in registers: f1/f2 by in-register + shuffle reduction,
//       V written transposed (bf16, single) via LDS bounce. No XW buffer.
//   K3: fused mask-pack + MFMA attention. Block = 16 rows x JLEN cols x 4
//       heads(waves). Phase 1: ballot-pack own A-tile into LDS (A read once
//       device-wide, coalesced). Phase 2: P in MFMA A-layout (single bf16),
//       5 MFMA/cc (4 PV + 1 ones-rowsum). grid (256,8) = 8 blocks/CU.
//       No max-subtraction (scores bounded -> softmax exact without it).
//   K4: combine njb j-partials, normalize, ELU.
// ws: pacc njb*4MB | f1h | f2h | Vhi 2MB | plsum. njb = 8 if fits else 4.

#define NN   4096
#define FIN  512
#define H    4
#define F    64
#define HF   256
#define LOG2E 1.44269504088896340736f

typedef __attribute__((ext_vector_type(4))) float f32x4;
typedef __attribute__((ext_vector_type(8))) short short8;

// ---------------- K1: fused GEMM + scores + bf16 transpose ----------------
// grid (128, 4): bi = 32-row block, h = head. 256 threads.
// thread (tx=t&15, ty=t>>4): rows ty*2+{0,1}, cols tx*4+{0..3} of 32x64 tile.
__global__ __launch_bounds__(256) void gemm_scores_fused(
        const float* __restrict__ X, const float* __restrict__ W,
        const float* __restrict__ a_src, const float* __restrict__ a_dst,
        float* __restrict__ f1h, float* __restrict__ f2h,
        unsigned short* __restrict__ Vhi) {
    __shared__ float Ast[32][34];            // [k][m], pad->8B aligned float2
    __shared__ float Bs[32][64];             // [k][n]
    __shared__ unsigned short Vt[64][40];    // [f][n], pad->16B aligned rows

    const int bi = blockIdx.x, h = blockIdx.y;
    const int t  = threadIdx.x;
    const int tx = t & 15, ty = t >> 4;

    float acc[2][4];
#pragma unroll
    for (int r = 0; r < 2; ++r)
#pragma unroll
        for (int c = 0; c < 4; ++c) acc[r][c] = 0.f;

    const int ar = t >> 3, ak = (t & 7) * 4;     // A load: row, 4 k's
    const int bk = t >> 3, bn = (t & 7) * 8;     // B load: k, 8 n's

    const float* Ap = X + (size_t)(bi * 32 + ar) * FIN + ak;
    const float* Bp = W + (size_t)bk * HF + h * F + bn;

    for (int k0 = 0; k0 < FIN; k0 += 32) {
        float4 av = *(const float4*)(Ap + k0);
        float4 bv0 = *(const float4*)(Bp + (size_t)k0 * HF);
        float4 bv1 = *(const float4*)(Bp + (size_t)k0 * HF + 4);
        __syncthreads();
        Ast[ak + 0][ar] = av.x;
        Ast[ak + 1][ar] = av.y;
        Ast[ak + 2][ar] = av.z;
        Ast[ak + 3][ar] = av.w;
        *(float4*)&Bs[bk][bn] = bv0;
        *(float4*)&Bs[bk][bn + 4] = bv1;
        __syncthreads();
#pragma unroll
        for (int kk = 0; kk < 32; ++kk) {
            float2 a2 = *(const float2*)&Ast[kk][ty * 2];
            float4 b4 = *(const float4*)&Bs[kk][tx * 4];
            acc[0][0] += a2.x * b4.x; acc[0][1] += a2.x * b4.y;
            acc[0][2] += a2.x * b4.z; acc[0][3] += a2.x * b4.w;
            acc[1][0] += a2.y * b4.x; acc[1][1] += a2.y * b4.y;
            acc[1][2] += a2.y * b4.z; acc[1][3] += a2.y * b4.w;
        }
    }

    // ---- scores: s1/s2 per row, reduce over the 16 tx lanes (width-16) ----
    float4 as4 = *(const float4*)(a_src + h * F + tx * 4);
    float4 ad4 = *(const float4*)(a_dst + h * F + tx * 4);
#pragma unroll
    for (int r = 0; r < 2; ++r) {
        float s1 = acc[r][0] * as4.x + acc[r][1] * as4.y
                 + acc[r][2] * as4.z + acc[r][3] * as4.w;
        float s2 = acc[r][0] * ad4.x + acc[r][1] * ad4.y
                 + acc[r][2] * ad4.z + acc[r][3] * ad4.w;
#pragma unroll
        for (int off = 1; off < 16; off <<= 1) {
            s1 += __shfl_xor(s1, off, 16);
            s2 += __shfl_xor(s2, off, 16);
        }
        if (tx == 0) {
            const int n = bi * 32 + ty * 2 + r;
            f1h[h * NN + n] = s1 * LOG2E;
            f2h[h * NN + n] = s2 * LOG2E;
        }
    }

    // ---- transposed bf16 V via LDS bounce ----
    __syncthreads();   // Bs reads done (Vt is separate, but keep order clean)
#pragma unroll
    for (int r = 0; r < 2; ++r)
#pragma unroll
        for (int c = 0; c < 4; ++c) {
            __hip_bfloat16 b = __float2bfloat16(acc[r][c]);
            Vt[tx * 4 + c][ty * 2 + r] = __builtin_bit_cast(unsigned short, b);
        }
    __syncthreads();
    {
        const int f = t >> 2, ch = t & 3;        // 64 f-rows x 4 chunks of 8
        short8 v = *(const short8*)&Vt[f][ch * 8];
        *(short8*)&Vhi[(size_t)(h * F + f) * NN + bi * 32 + ch * 8] = v;
    }
}

// ---------------- K3: fused mask-pack + MFMA attention ----------------
// grid (256, njb): ib = 16-row block, jb = JLEN-col strip. wave = head.
// Phase 1: ballot-pack A tile (16 x JLEN) -> LDS bitmask (read coalesced,
// each A element read exactly once device-wide). Phase 2: MFMA PV.
template <int JLEN>
__global__ __launch_bounds__(256) void gat_fused(
        const int* __restrict__ A,
        const unsigned short* __restrict__ Vhi,
        const float* __restrict__ f1h, const float* __restrict__ f2h,
        float* __restrict__ pacc, float* __restrict__ plsum) {
    constexpr int NCC = JLEN / 32;
    constexpr int WPR = JLEN / 64;               // u64 words per row
    __shared__ unsigned long long mask64[16][WPR];

    const int ib = blockIdx.x, jb = blockIdx.y;
    const int w    = threadIdx.x >> 6;
    const int lane = threadIdx.x & 63;

    // ---- phase 1: ballot-pack own A tile ----
    {
        constexpr int TW = 16 * WPR / 4;         // ballots per wave
        const int* Abase = A + (size_t)(ib * 16) * NN + jb * JLEN;
#pragma unroll 4
        for (int it = 0; it < TW; ++it) {
            const int idx = w * TW + it;
            const int r = idx / WPR, wc = idx % WPR;
            int a = Abase[(size_t)r * NN + wc * 64 + lane];
            unsigned long long m = __ballot(a != 0);
            if (lane == 0) mask64[r][wc] = m;
        }
    }
    __syncthreads();

    // ---- phase 2: MFMA attention ----
    const int h  = w;
    const int il = lane & 15;        // MFMA A row / B,C/D col
    const int kg = lane >> 4;        // k-group
    const int sh = kg * 8;
    const int i0 = ib * 16 + il;

    const float c0 = f1h[h * NN + i0];
    const unsigned int* m32 = (const unsigned int*)&mask64[il][0];
    const float* f2p = f2h + (size_t)h * NN + jb * JLEN;

    f32x4 acc[4], lac;
#pragma unroll
    for (int ft = 0; ft < 4; ++ft) acc[ft] = (f32x4){0.f, 0.f, 0.f, 0.f};
    lac = (f32x4){0.f, 0.f, 0.f, 0.f};

    short8 ones;
#pragma unroll
    for (int e = 0; e < 8; ++e) ones[e] = (short)0x3F80;   // bf16 1.0

#pragma unroll 2
    for (int cc = 0; cc < NCC; ++cc) {
        const unsigned int m0 = m32[cc] >> sh;

        float4 ga = *(const float4*)(f2p + cc * 32 + sh);
        float4 gb = *(const float4*)(f2p + cc * 32 + sh + 4);
        float gv[8] = {ga.x, ga.y, ga.z, ga.w, gb.x, gb.y, gb.z, gb.w};

        short8 pa;
#pragma unroll
        for (int e = 0; e < 8; ++e) {
            float s = c0 + gv[e];
            s = fmaxf(s, 0.2f * s);              // leaky relu (x log2e commutes)
            float q = exp2f(s);                  // no max-sub: s bounded
            q = ((m0 >> e) & 1u) ? q : 0.f;
            pa[e] = __builtin_bit_cast(short, __float2bfloat16(q));
        }

        const int jl = jb * JLEN + cc * 32 + sh;
#pragma unroll
        for (int ft = 0; ft < 4; ++ft) {
            short8 bh = *reinterpret_cast<const short8*>(
                Vhi + (size_t)(h * F + ft * 16 + il) * NN + jl);
            acc[ft] = __builtin_amdgcn_mfma_f32_16x16x32_bf16(pa, bh, acc[ft], 0, 0, 0);
        }
        lac = __builtin_amdgcn_mfma_f32_16x16x32_bf16(pa, ones, lac, 0, 0, 0);
    }

    // C/D layout: col = lane&15, row = (lane>>4)*4 + reg
    float* pb = pacc + (size_t)jb * NN * HF + (size_t)(ib * 16) * HF;
#pragma unroll
    for (int ft = 0; ft < 4; ++ft)
#pragma unroll
        for (int r = 0; r < 4; ++r)
            pb[(kg * 4 + r) * HF + h * F + ft * 16 + il] = acc[ft][r];

    if (il == 0) {   // ones-MFMA: every col holds the row sum; use col 0
#pragma unroll
        for (int r = 0; r < 4; ++r)
            plsum[(size_t)jb * NN * H + (size_t)(ib * 16 + kg * 4 + r) * H + h] = lac[r];
    }
}

// ---------------- K4: combine partials, normalize, ELU ----------------
__global__ __launch_bounds__(256) void finalize(
        const float* __restrict__ pacc, const float* __restrict__ plsum,
        const unsigned short* __restrict__ Vhi, float* __restrict__ out,
        int njb) {
    const int gid = blockIdx.x * 256 + threadIdx.x;   // 0 .. NN*HF-1
    const int i = gid >> 8, hf = gid & 255, h = hf >> 6;
    float a = 0.f, l = 0.f;
    for (int jb = 0; jb < njb; ++jb) {
        a += pacc[(size_t)jb * NN * HF + gid];
        l += plsum[(size_t)jb * NN * H + (size_t)i * H + h];
    }
    if (l == 0.f) {   // empty row: reference softmax degenerates to uniform
        float s = 0.f;
        const unsigned short* col = Vhi + (size_t)hf * NN;
        for (int j = 0; j < NN; ++j)
            s += __uint_as_float(((unsigned int)col[j]) << 16);
        a = s; l = (float)NN;
    }
    float o = a / l;
    out[gid] = (o > 0.f) ? o : (exp2f(o * LOG2E) - 1.f);
}

// ---------------- launch ----------------
extern "C" void kernel_launch(void* const* d_in, const int* in_sizes, int n_in,
                              void* d_out, int out_size, void* d_ws, size_t ws_size,
                              hipStream_t stream) {
    const float* X     = (const float*)d_in[0];
    const int*   A     = (const int*)d_in[1];
    const float* W     = (const float*)d_in[2];
    const float* a_src = (const float*)d_in[3];
    const float* a_dst = (const float*)d_in[4];
    float* out = (float*)d_out;

    // ws need: pacc njb*NN*HF*4 | f1h,f2h 2*NN*H*4 | Vhi HF*NN*2 | plsum njb*NN*H*4
    const size_t fixed = (size_t)2 * NN * H * 4 + (size_t)HF * NN * 2;
    auto need = [&](int njb) {
        return (size_t)njb * NN * HF * 4 + (size_t)njb * NN * H * 4 + fixed;
    };
    const int njb = (ws_size >= need(8)) ? 8 : 4;   // deterministic in ws_size

    float* pacc = (float*)d_ws;
    float* f1h  = pacc + (size_t)njb * NN * HF;
    float* f2h  = f1h + (size_t)NN * H;
    unsigned short* Vhi = (unsigned short*)(f2h + (size_t)NN * H);
    float* plsum = (float*)(Vhi + (size_t)HF * NN);

    gemm_scores_fused<<<dim3(128, 4), 256, 0, stream>>>(X, W, a_src, a_dst,
                                                        f1h, f2h, Vhi);
    if (njb == 8)
        gat_fused<512><<<dim3(256, 8), 256, 0, stream>>>(A, Vhi, f1h, f2h,
                                                         pacc, plsum);
    else
        gat_fused<1024><<<dim3(256, 4), 256, 0, stream>>>(A, Vhi, f1h, f2h,
                                                          pacc, plsum);
    finalize<<<NN * HF / 256, 256, 0, stream>>>(pacc, plsum, Vhi, out, njb);
}

// Round 7
// 95.850 us; speedup vs baseline: 1.7034x; 1.2352x over previous
//
#include <hip/hip_runtime.h>
#include <hip/hip_bf16.h>

// GAT layer, N=4096, FIN=512, H=4 heads, F=64.
// R7: best-of-R5/R6 recombination.
//   K0: pack_mask — A -> 2MB bitmask, perfectly-sequential streaming ballot
//       (R6 proved in-kernel packing costs ~25us; separate pass is ~12us).
//   K1: fused GEMM+scores+bf16-V-transpose (R6, unchanged).
//   K3: 32 rows x JLEN cols x 4 heads(waves); mask = broadcast dwords from
//       L2; single-bf16 P and V (absmax 2e-3 vs 9.8e-3 threshold, proven);
//       10 MFMA/cc (8 PV + 2 ones-rowsum); V loads shared by 2 rowtiles.
//       No max-subtraction (scores bounded -> softmax exact without it).
//   K4: combine njb j-partials, normalize, ELU.
// ws: pacc njb*4MB | f1h | f2h | Vhi 2MB | plsum | Ab 2MB. njb: 8 else 4.

#define NN   4096
#define FIN  512
#define H    4
#define F    64
#define HF   256
#define LOG2E 1.44269504088896340736f

typedef __attribute__((ext_vector_type(4))) float f32x4;
typedef __attribute__((ext_vector_type(8))) short short8;

// ---------------- K0: bit-pack adjacency (streaming) ----------------
__global__ __launch_bounds__(256) void pack_mask(const int* __restrict__ A,
                                                 unsigned long long* __restrict__ Ab) {
    const int gw   = (blockIdx.x * 256 + threadIdx.x) >> 6;   // global wave id
    const int lane = threadIdx.x & 63;
    const int nchunk = NN * NN / 64;                          // 262144
    for (int c = gw; c < nchunk; c += 8192) {                 // 2048 blk * 4 waves
        int a = A[(size_t)c * 64 + lane];
        unsigned long long m = __ballot(a != 0);
        if (lane == 0) Ab[c] = m;
    }
}

// ---------------- K1: fused GEMM + scores + bf16 transpose ----------------
// grid (128, 4): bi = 32-row block, h = head. 256 threads.
__global__ __launch_bounds__(256) void gemm_scores_fused(
        const float* __restrict__ X, const float* __restrict__ W,
        const float* __restrict__ a_src, const float* __restrict__ a_dst,
        float* __restrict__ f1h, float* __restrict__ f2h,
        unsigned short* __restrict__ Vhi) {
    __shared__ float Ast[32][34];            // [k][m]
    __shared__ float Bs[32][64];             // [k][n]
    __shared__ unsigned short Vt[64][40];    // [f][n]

    const int bi = blockIdx.x, h = blockIdx.y;
    const int t  = threadIdx.x;
    const int tx = t & 15, ty = t >> 4;

    float acc[2][4];
#pragma unroll
    for (int r = 0; r < 2; ++r)
#pragma unroll
        for (int c = 0; c < 4; ++c) acc[r][c] = 0.f;

    const int ar = t >> 3, ak = (t & 7) * 4;
    const int bk = t >> 3, bn = (t & 7) * 8;

    const float* Ap = X + (size_t)(bi * 32 + ar) * FIN + ak;
    const float* Bp = W + (size_t)bk * HF + h * F + bn;

    for (int k0 = 0; k0 < FIN; k0 += 32) {
        float4 av  = *(const float4*)(Ap + k0);
        float4 bv0 = *(const float4*)(Bp + (size_t)k0 * HF);
        float4 bv1 = *(const float4*)(Bp + (size_t)k0 * HF + 4);
        __syncthreads();
        Ast[ak + 0][ar] = av.x;
        Ast[ak + 1][ar] = av.y;
        Ast[ak + 2][ar] = av.z;
        Ast[ak + 3][ar] = av.w;
        *(float4*)&Bs[bk][bn] = bv0;
        *(float4*)&Bs[bk][bn + 4] = bv1;
        __syncthreads();
#pragma unroll
        for (int kk = 0; kk < 32; ++kk) {
            float2 a2 = *(const float2*)&Ast[kk][ty * 2];
            float4 b4 = *(const float4*)&Bs[kk][tx * 4];
            acc[0][0] += a2.x * b4.x; acc[0][1] += a2.x * b4.y;
            acc[0][2] += a2.x * b4.z; acc[0][3] += a2.x * b4.w;
            acc[1][0] += a2.y * b4.x; acc[1][1] += a2.y * b4.y;
            acc[1][2] += a2.y * b4.z; acc[1][3] += a2.y * b4.w;
        }
    }

    // scores: per-row dot with a_src/a_dst, reduce over 16 tx lanes
    float4 as4 = *(const float4*)(a_src + h * F + tx * 4);
    float4 ad4 = *(const float4*)(a_dst + h * F + tx * 4);
#pragma unroll
    for (int r = 0; r < 2; ++r) {
        float s1 = acc[r][0] * as4.x + acc[r][1] * as4.y
                 + acc[r][2] * as4.z + acc[r][3] * as4.w;
        float s2 = acc[r][0] * ad4.x + acc[r][1] * ad4.y
                 + acc[r][2] * ad4.z + acc[r][3] * ad4.w;
#pragma unroll
        for (int off = 1; off < 16; off <<= 1) {
            s1 += __shfl_xor(s1, off, 16);
            s2 += __shfl_xor(s2, off, 16);
        }
        if (tx == 0) {
            const int n = bi * 32 + ty * 2 + r;
            f1h[h * NN + n] = s1 * LOG2E;
            f2h[h * NN + n] = s2 * LOG2E;
        }
    }

    // transposed bf16 V via LDS bounce
    __syncthreads();
#pragma unroll
    for (int r = 0; r < 2; ++r)
#pragma unroll
        for (int c = 0; c < 4; ++c) {
            __hip_bfloat16 b = __float2bfloat16(acc[r][c]);
            Vt[tx * 4 + c][ty * 2 + r] = __builtin_bit_cast(unsigned short, b);
        }
    __syncthreads();
    {
        const int f = t >> 2, ch = t & 3;
        short8 v = *(const short8*)&Vt[f][ch * 8];
        *(short8*)&Vhi[(size_t)(h * F + f) * NN + bi * 32 + ch * 8] = v;
    }
}

// ---------------- K3: MFMA fused attention (partials) ----------------
// grid (128, njb): ib = 32-row block, jb = JLEN-col strip. wave = head.
template <int JLEN>
__global__ __launch_bounds__(256) void gat_attn_mfma(
        const unsigned int* __restrict__ Ab32,
        const unsigned short* __restrict__ Vhi,
        const float* __restrict__ f1h, const float* __restrict__ f2h,
        float* __restrict__ pacc, float* __restrict__ plsum) {
    constexpr int NCC = JLEN / 32;
    const int ib = blockIdx.x, jb = blockIdx.y;
    const int h    = threadIdx.x >> 6;
    const int lane = threadIdx.x & 63;
    const int il = lane & 15;        // MFMA A row / B,C/D col
    const int kg = lane >> 4;        // k-group
    const int sh = kg * 8;
    const int i0 = ib * 32 + il;
    const int i1 = i0 + 16;

    const float c0 = f1h[h * NN + i0];
    const float c1 = f1h[h * NN + i1];

    const unsigned int* ab0 = Ab32 + (size_t)i0 * (NN / 32) + jb * (JLEN / 32);
    const unsigned int* ab1 = Ab32 + (size_t)i1 * (NN / 32) + jb * (JLEN / 32);
    const float* f2p = f2h + (size_t)h * NN + jb * JLEN;

    f32x4 acc0[4], acc1[4], lac0, lac1;
#pragma unroll
    for (int ft = 0; ft < 4; ++ft) {
        acc0[ft] = (f32x4){0.f, 0.f, 0.f, 0.f};
        acc1[ft] = (f32x4){0.f, 0.f, 0.f, 0.f};
    }
    lac0 = (f32x4){0.f, 0.f, 0.f, 0.f};
    lac1 = (f32x4){0.f, 0.f, 0.f, 0.f};

    short8 ones;
#pragma unroll
    for (int e = 0; e < 8; ++e) ones[e] = (short)0x3F80;   // bf16 1.0

#pragma unroll 4
    for (int cc = 0; cc < NCC; ++cc) {
        const unsigned int m0 = ab0[cc] >> sh;   // L2/L1-resident broadcast
        const unsigned int m1 = ab1[cc] >> sh;

        float4 ga = *(const float4*)(f2p + cc * 32 + sh);
        float4 gb = *(const float4*)(f2p + cc * 32 + sh + 4);
        float gv[8] = {ga.x, ga.y, ga.z, ga.w, gb.x, gb.y, gb.z, gb.w};

        short8 pa0, pa1;
#pragma unroll
        for (int e = 0; e < 8; ++e) {
            float s0 = c0 + gv[e];
            s0 = fmaxf(s0, 0.2f * s0);           // leaky relu (x log2e commutes)
            float q0 = exp2f(s0);                // no max-sub: s bounded
            q0 = ((m0 >> e) & 1u) ? q0 : 0.f;
            pa0[e] = __builtin_bit_cast(short, __float2bfloat16(q0));
            float s1 = c1 + gv[e];
            s1 = fmaxf(s1, 0.2f * s1);
            float q1 = exp2f(s1);
            q1 = ((m1 >> e) & 1u) ? q1 : 0.f;
            pa1[e] = __builtin_bit_cast(short, __float2bfloat16(q1));
        }

        const int jl = jb * JLEN + cc * 32 + sh;
#pragma unroll
        for (int ft = 0; ft < 4; ++ft) {
            short8 bh = *reinterpret_cast<const short8*>(
                Vhi + (size_t)(h * F + ft * 16 + il) * NN + jl);
            acc0[ft] = __builtin_amdgcn_mfma_f32_16x16x32_bf16(pa0, bh, acc0[ft], 0, 0, 0);
            acc1[ft] = __builtin_amdgcn_mfma_f32_16x16x32_bf16(pa1, bh, acc1[ft], 0, 0, 0);
        }
        lac0 = __builtin_amdgcn_mfma_f32_16x16x32_bf16(pa0, ones, lac0, 0, 0, 0);
        lac1 = __builtin_amdgcn_mfma_f32_16x16x32_bf16(pa1, ones, lac1, 0, 0, 0);
    }

    // C/D layout: col = lane&15, row = (lane>>4)*4 + reg
    float* pb = pacc + (size_t)jb * NN * HF + (size_t)(ib * 32) * HF;
#pragma unroll
    for (int ft = 0; ft < 4; ++ft)
#pragma unroll
        for (int r = 0; r < 4; ++r) {
            pb[(kg * 4 + r) * HF + h * F + ft * 16 + il]      = acc0[ft][r];
            pb[(16 + kg * 4 + r) * HF + h * F + ft * 16 + il] = acc1[ft][r];
        }

    if (il == 0) {   // ones-MFMA: every col holds the row sum; use col 0
#pragma unroll
        for (int r = 0; r < 4; ++r) {
            plsum[(size_t)jb * NN * H + (size_t)(ib * 32 + kg * 4 + r) * H + h]      = lac0[r];
            plsum[(size_t)jb * NN * H + (size_t)(ib * 32 + 16 + kg * 4 + r) * H + h] = lac1[r];
        }
    }
}

// ---------------- K4: combine partials, normalize, ELU ----------------
__global__ __launch_bounds__(256) void finalize(
        const float* __restrict__ pacc, const float* __restrict__ plsum,
        const unsigned short* __restrict__ Vhi, float* __restrict__ out,
        int njb) {
    const int gid = blockIdx.x * 256 + threadIdx.x;   // 0 .. NN*HF-1
    const int i = gid >> 8, hf = gid & 255, h = hf >> 6;
    float a = 0.f, l = 0.f;
    for (int jb = 0; jb < njb; ++jb) {
        a += pacc[(size_t)jb * NN * HF + gid];
        l += plsum[(size_t)jb * NN * H + (size_t)i * H + h];
    }
    if (l == 0.f) {   // empty row: reference softmax degenerates to uniform
        float s = 0.f;
        const unsigned short* col = Vhi + (size_t)hf * NN;
        for (int j = 0; j < NN; ++j)
            s += __uint_as_float(((unsigned int)col[j]) << 16);
        a = s; l = (float)NN;
    }
    float o = a / l;
    out[gid] = (o > 0.f) ? o : (exp2f(o * LOG2E) - 1.f);
}

// ---------------- launch ----------------
extern "C" void kernel_launch(void* const* d_in, const int* in_sizes, int n_in,
                              void* d_out, int out_size, void* d_ws, size_t ws_size,
                              hipStream_t stream) {
    const float* X     = (const float*)d_in[0];
    const int*   A     = (const int*)d_in[1];
    const float* W     = (const float*)d_in[2];
    const float* a_src = (const float*)d_in[3];
    const float* a_dst = (const float*)d_in[4];
    float* out = (float*)d_out;

    // ws: pacc njb*NN*HF*4 | f1h,f2h | Vhi HF*NN*2 | plsum | Ab NN*NN/8
    const size_t fixed = (size_t)2 * NN * H * 4 + (size_t)HF * NN * 2
                       + (size_t)NN * NN / 8;
    auto need = [&](int njb) {
        return (size_t)njb * NN * HF * 4 + (size_t)njb * NN * H * 4 + fixed;
    };
    const int njb = (ws_size >= need(8)) ? 8 : 4;   // deterministic in ws_size

    float* pacc = (float*)d_ws;
    float* f1h  = pacc + (size_t)njb * NN * HF;
    float* f2h  = f1h + (size_t)NN * H;
    unsigned short* Vhi = (unsigned short*)(f2h + (size_t)NN * H);
    float* plsum = (float*)(Vhi + (size_t)HF * NN);
    unsigned long long* Ab = (unsigned long long*)(plsum + (size_t)njb * NN * H);

    pack_mask<<<2048, 256, 0, stream>>>(A, Ab);
    gemm_scores_fused<<<dim3(128, 4), 256, 0, stream>>>(X, W, a_src, a_dst,
                                                        f1h, f2h, Vhi);
    if (njb == 8)
        gat_attn_mfma<512><<<dim3(128, 8), 256, 0, stream>>>(
            (const unsigned int*)Ab, Vhi, f1h, f2h, pacc, plsum);
    else
        gat_attn_mfma<1024><<<dim3(128, 4), 256, 0, stream>>>(
            (const unsigned int*)Ab, Vhi, f1h, f2h, pacc, plsum);
    finalize<<<NN * HF / 256, 256, 0, stream>>>(pacc, plsum, Vhi, out, njb);
}

// Round 8
// 81.789 us; speedup vs baseline: 1.9962x; 1.1719x over previous
//
#include <hip/hip_runtime.h>
#include <hip/hip_bf16.h>

// GAT layer, N=4096, FIN=512, H=4 heads, F=64.
// R8: VALU + overlap attack (R7 post-mortem: exp2f = OCML call ~10 instrs,
// explains VALUBusy 54% anomaly; pack & gemm serialized but independent).
//   K01: heterogeneous kernel — blocks <512: fused GEMM+scores+bf16-V-
//        transpose; blocks >=512: grid-stride ballot mask-pack (A 64MB
//        stream overlaps GEMM compute).
//   K3:  32 rows x JLEN x 4 heads(waves); raw v_exp_f32 via
//        __builtin_amdgcn_exp2f (scores bounded, no range handling needed);
//        10 MFMA/cc; no max-subtraction (softmax exact without it).
//   K4:  float4-vectorized combine, normalize, ELU.
// ws: pacc njb*4MB | f1h | f2h | Vhi 2MB | plsum | Ab 2MB. njb: 8 else 4.

#define NN   4096
#define FIN  512
#define H    4
#define F    64
#define HF   256
#define LOG2E 1.44269504088896340736f

typedef __attribute__((ext_vector_type(4))) float f32x4;
typedef __attribute__((ext_vector_type(8))) short short8;

// ---------------- K01: fused (GEMM+scores+transpose) | mask-pack ----------
// grid 1536: blocks 0..511 = gemm (bi = b&127, h = b>>7), 512..1535 = pack.
__global__ __launch_bounds__(256) void gemm_scores_pack(
        const float* __restrict__ X, const float* __restrict__ W,
        const float* __restrict__ a_src, const float* __restrict__ a_dst,
        const int* __restrict__ A,
        float* __restrict__ f1h, float* __restrict__ f2h,
        unsigned short* __restrict__ Vhi,
        unsigned long long* __restrict__ Ab) {
    if (blockIdx.x >= 512) {
        // ---- mask pack: streaming ballot, A read once, coalesced ----
        const int pb   = blockIdx.x - 512;                    // 0..1023
        const int gw   = (pb * 256 + threadIdx.x) >> 6;       // global wave
        const int lane = threadIdx.x & 63;
        const int nchunk = NN * NN / 64;                      // 262144
        for (int c = gw; c < nchunk; c += 4096) {
            int a = A[(size_t)c * 64 + lane];
            unsigned long long m = __ballot(a != 0);
            if (lane == 0) Ab[c] = m;
        }
        return;
    }

    __shared__ float Ast[32][34];            // [k][m]
    __shared__ float Bs[32][64];             // [k][n]
    __shared__ unsigned short Vt[64][40];    // [f][n]

    const int bi = blockIdx.x & 127, h = blockIdx.x >> 7;
    const int t  = threadIdx.x;
    const int tx = t & 15, ty = t >> 4;

    float acc[2][4];
#pragma unroll
    for (int r = 0; r < 2; ++r)
#pragma unroll
        for (int c = 0; c < 4; ++c) acc[r][c] = 0.f;

    const int ar = t >> 3, ak = (t & 7) * 4;
    const int bk = t >> 3, bn = (t & 7) * 8;

    const float* Ap = X + (size_t)(bi * 32 + ar) * FIN + ak;
    const float* Bp = W + (size_t)bk * HF + h * F + bn;

    for (int k0 = 0; k0 < FIN; k0 += 32) {
        float4 av  = *(const float4*)(Ap + k0);
        float4 bv0 = *(const float4*)(Bp + (size_t)k0 * HF);
        float4 bv1 = *(const float4*)(Bp + (size_t)k0 * HF + 4);
        __syncthreads();
        Ast[ak + 0][ar] = av.x;
        Ast[ak + 1][ar] = av.y;
        Ast[ak + 2][ar] = av.z;
        Ast[ak + 3][ar] = av.w;
        *(float4*)&Bs[bk][bn] = bv0;
        *(float4*)&Bs[bk][bn + 4] = bv1;
        __syncthreads();
#pragma unroll
        for (int kk = 0; kk < 32; ++kk) {
            float2 a2 = *(const float2*)&Ast[kk][ty * 2];
            float4 b4 = *(const float4*)&Bs[kk][tx * 4];
            acc[0][0] += a2.x * b4.x; acc[0][1] += a2.x * b4.y;
            acc[0][2] += a2.x * b4.z; acc[0][3] += a2.x * b4.w;
            acc[1][0] += a2.y * b4.x; acc[1][1] += a2.y * b4.y;
            acc[1][2] += a2.y * b4.z; acc[1][3] += a2.y * b4.w;
        }
    }

    // scores: per-row dot with a_src/a_dst, reduce over 16 tx lanes
    float4 as4 = *(const float4*)(a_src + h * F + tx * 4);
    float4 ad4 = *(const float4*)(a_dst + h * F + tx * 4);
#pragma unroll
    for (int r = 0; r < 2; ++r) {
        float s1 = acc[r][0] * as4.x + acc[r][1] * as4.y
                 + acc[r][2] * as4.z + acc[r][3] * as4.w;
        float s2 = acc[r][0] * ad4.x + acc[r][1] * ad4.y
                 + acc[r][2] * ad4.z + acc[r][3] * ad4.w;
#pragma unroll
        for (int off = 1; off < 16; off <<= 1) {
            s1 += __shfl_xor(s1, off, 16);
            s2 += __shfl_xor(s2, off, 16);
        }
        if (tx == 0) {
            const int n = bi * 32 + ty * 2 + r;
            f1h[h * NN + n] = s1 * LOG2E;
            f2h[h * NN + n] = s2 * LOG2E;
        }
    }

    // transposed bf16 V via LDS bounce
    __syncthreads();
#pragma unroll
    for (int r = 0; r < 2; ++r)
#pragma unroll
        for (int c = 0; c < 4; ++c) {
            __hip_bfloat16 b = __float2bfloat16(acc[r][c]);
            Vt[tx * 4 + c][ty * 2 + r] = __builtin_bit_cast(unsigned short, b);
        }
    __syncthreads();
    {
        const int f = t >> 2, ch = t & 3;
        short8 v = *(const short8*)&Vt[f][ch * 8];
        *(short8*)&Vhi[(size_t)(h * F + f) * NN + bi * 32 + ch * 8] = v;
    }
}

// ---------------- K3: MFMA fused attention (partials) ----------------
// grid (128, njb): ib = 32-row block, jb = JLEN-col strip. wave = head.
template <int JLEN>
__global__ __launch_bounds__(256) void gat_attn_mfma(
        const unsigned int* __restrict__ Ab32,
        const unsigned short* __restrict__ Vhi,
        const float* __restrict__ f1h, const float* __restrict__ f2h,
        float* __restrict__ pacc, float* __restrict__ plsum) {
    constexpr int NCC = JLEN / 32;
    const int ib = blockIdx.x, jb = blockIdx.y;
    const int h    = threadIdx.x >> 6;
    const int lane = threadIdx.x & 63;
    const int il = lane & 15;        // MFMA A row / B,C/D col
    const int kg = lane >> 4;        // k-group
    const int sh = kg * 8;
    const int i0 = ib * 32 + il;
    const int i1 = i0 + 16;

    const float c0 = f1h[h * NN + i0];
    const float c1 = f1h[h * NN + i1];

    const unsigned int* ab0 = Ab32 + (size_t)i0 * (NN / 32) + jb * (JLEN / 32);
    const unsigned int* ab1 = Ab32 + (size_t)i1 * (NN / 32) + jb * (JLEN / 32);
    const float* f2p = f2h + (size_t)h * NN + jb * JLEN;

    f32x4 acc0[4], acc1[4], lac0, lac1;
#pragma unroll
    for (int ft = 0; ft < 4; ++ft) {
        acc0[ft] = (f32x4){0.f, 0.f, 0.f, 0.f};
        acc1[ft] = (f32x4){0.f, 0.f, 0.f, 0.f};
    }
    lac0 = (f32x4){0.f, 0.f, 0.f, 0.f};
    lac1 = (f32x4){0.f, 0.f, 0.f, 0.f};

    short8 ones;
#pragma unroll
    for (int e = 0; e < 8; ++e) ones[e] = (short)0x3F80;   // bf16 1.0

#pragma unroll 4
    for (int cc = 0; cc < NCC; ++cc) {
        const unsigned int m0 = ab0[cc] >> sh;   // L2/L1-resident broadcast
        const unsigned int m1 = ab1[cc] >> sh;

        float4 ga = *(const float4*)(f2p + cc * 32 + sh);
        float4 gb = *(const float4*)(f2p + cc * 32 + sh + 4);
        float gv[8] = {ga.x, ga.y, ga.z, ga.w, gb.x, gb.y, gb.z, gb.w};

        short8 pa0, pa1;
#pragma unroll
        for (int e = 0; e < 8; ++e) {
            float s0 = c0 + gv[e];
            s0 = fmaxf(s0, 0.2f * s0);                  // leaky relu
            float q0 = __builtin_amdgcn_exp2f(s0);      // raw v_exp_f32
            q0 = ((m0 >> e) & 1u) ? q0 : 0.f;
            pa0[e] = __builtin_bit_cast(short, __float2bfloat16(q0));
            float s1 = c1 + gv[e];
            s1 = fmaxf(s1, 0.2f * s1);
            float q1 = __builtin_amdgcn_exp2f(s1);
            q1 = ((m1 >> e) & 1u) ? q1 : 0.f;
            pa1[e] = __builtin_bit_cast(short, __float2bfloat16(q1));
        }

        const int jl = jb * JLEN + cc * 32 + sh;
#pragma unroll
        for (int ft = 0; ft < 4; ++ft) {
            short8 bh = *reinterpret_cast<const short8*>(
                Vhi + (size_t)(h * F + ft * 16 + il) * NN + jl);
            acc0[ft] = __builtin_amdgcn_mfma_f32_16x16x32_bf16(pa0, bh, acc0[ft], 0, 0, 0);
            acc1[ft] = __builtin_amdgcn_mfma_f32_16x16x32_bf16(pa1, bh, acc1[ft], 0, 0, 0);
        }
        lac0 = __builtin_amdgcn_mfma_f32_16x16x32_bf16(pa0, ones, lac0, 0, 0, 0);
        lac1 = __builtin_amdgcn_mfma_f32_16x16x32_bf16(pa1, ones, lac1, 0, 0, 0);
    }

    // C/D layout: col = lane&15, row = (lane>>4)*4 + reg
    float* pb = pacc + (size_t)jb * NN * HF + (size_t)(ib * 32) * HF;
#pragma unroll
    for (int ft = 0; ft < 4; ++ft)
#pragma unroll
        for (int r = 0; r < 4; ++r) {
            pb[(kg * 4 + r) * HF + h * F + ft * 16 + il]      = acc0[ft][r];
            pb[(16 + kg * 4 + r) * HF + h * F + ft * 16 + il] = acc1[ft][r];
        }

    if (il == 0) {   // ones-MFMA: every col holds the row sum; use col 0
#pragma unroll
        for (int r = 0; r < 4; ++r) {
            plsum[(size_t)jb * NN * H + (size_t)(ib * 32 + kg * 4 + r) * H + h]      = lac0[r];
            plsum[(size_t)jb * NN * H + (size_t)(ib * 32 + 16 + kg * 4 + r) * H + h] = lac1[r];
        }
    }
}

// ---------------- K4: combine partials, normalize, ELU (float4) ----------
__global__ __launch_bounds__(256) void finalize(
        const float* __restrict__ pacc, const float* __restrict__ plsum,
        const unsigned short* __restrict__ Vhi, float* __restrict__ out,
        int njb) {
    const int gid4 = blockIdx.x * 256 + threadIdx.x;   // 0 .. NN*HF/4-1
    const int i = gid4 >> 6, q = gid4 & 63;            // row, quad-in-row
    const int h = q >> 4;                              // head (uniform per quad)
    float4 a = make_float4(0.f, 0.f, 0.f, 0.f);
    float l = 0.f;
    for (int jb = 0; jb < njb; ++jb) {
        float4 p = *(const float4*)&pacc[(size_t)jb * NN * HF + (size_t)i * HF + q * 4];
        a.x += p.x; a.y += p.y; a.z += p.z; a.w += p.w;
        l += plsum[(size_t)jb * NN * H + (size_t)i * H + h];
    }
    float av[4] = {a.x, a.y, a.z, a.w};
    if (l == 0.f) {   // empty row: reference softmax degenerates to uniform
#pragma unroll
        for (int c = 0; c < 4; ++c) {
            const unsigned short* col = Vhi + (size_t)(q * 4 + c) * NN;
            float s = 0.f;
            for (int j = 0; j < NN; ++j)
                s += __uint_as_float(((unsigned int)col[j]) << 16);
            av[c] = s;
        }
        l = (float)NN;
    }
    const float rl = 1.0f / l;
    float4 o;
    float* op = &o.x;
#pragma unroll
    for (int c = 0; c < 4; ++c) {
        float v = av[c] * rl;
        op[c] = (v > 0.f) ? v : (__builtin_amdgcn_exp2f(v * LOG2E) - 1.f);
    }
    *(float4*)&out[(size_t)i * HF + q * 4] = o;
}

// ---------------- launch ----------------
extern "C" void kernel_launch(void* const* d_in, const int* in_sizes, int n_in,
                              void* d_out, int out_size, void* d_ws, size_t ws_size,
                              hipStream_t stream) {
    const float* X     = (const float*)d_in[0];
    const int*   A     = (const int*)d_in[1];
    const float* W     = (const float*)d_in[2];
    const float* a_src = (const float*)d_in[3];
    const float* a_dst = (const float*)d_in[4];
    float* out = (float*)d_out;

    // ws: pacc njb*NN*HF*4 | f1h,f2h | Vhi HF*NN*2 | plsum | Ab NN*NN/8
    const size_t fixed = (size_t)2 * NN * H * 4 + (size_t)HF * NN * 2
                       + (size_t)NN * NN / 8;
    auto need = [&](int njb) {
        return (size_t)njb * NN * HF * 4 + (size_t)njb * NN * H * 4 + fixed;
    };
    const int njb = (ws_size >= need(8)) ? 8 : 4;   // deterministic in ws_size

    float* pacc = (float*)d_ws;
    float* f1h  = pacc + (size_t)njb * NN * HF;
    float* f2h  = f1h + (size_t)NN * H;
    unsigned short* Vhi = (unsigned short*)(f2h + (size_t)NN * H);
    float* plsum = (float*)(Vhi + (size_t)HF * NN);
    unsigned long long* Ab = (unsigned long long*)(plsum + (size_t)njb * NN * H);

    gemm_scores_pack<<<1536, 256, 0, stream>>>(X, W, a_src, a_dst, A,
                                               f1h, f2h, Vhi, Ab);
    if (njb == 8)
        gat_attn_mfma<512><<<dim3(128, 8), 256, 0, stream>>>(
            (const unsigned int*)Ab, Vhi, f1h, f2h, pacc, plsum);
    else
        gat_attn_mfma<1024><<<dim3(128, 4), 256, 0, stream>>>(
            (const unsigned int*)Ab, Vhi, f1h, f2h, pacc, plsum);
    finalize<<<NN * HF / 4 / 256, 256, 0, stream>>>(pacc, plsum, Vhi, out, njb);
}

// Round 9
// 81.191 us; speedup vs baseline: 2.0109x; 1.0074x over previous
//
#include <hip/hip_runtime.h>
#include <hip/hip_bf16.h>

// GAT layer, N=4096, FIN=512, H=4 heads, F=64.
// R9: K3 VALU cut. R5/R6 proved P-rounding doesn't move absmax (exact-split
// and RNE-bf16 P both gave 1.953e-3) -> truncation-pack P with v_perm
// (1 instr / 2 elems, replaces RNE cvt+pack ~14). Hoisted per-ft V base
// pointers (32-bit offsets in-loop). Raw v_exp_f32. Rest as R8.
//   K01: heterogeneous — blocks<512: GEMM+scores+bf16-V-transpose;
//        blocks>=512: grid-stride ballot mask-pack (overlapped).
//   K3:  32 rows x JLEN x 4 heads(waves); 10 MFMA/cc; no max-subtraction
//        (scores bounded -> softmax exact without it).
//   K4:  float4 combine, normalize, ELU.
// ws: pacc njb*4MB | f1h | f2h | Vhi 2MB | plsum | Ab 2MB. njb: 8 else 4.

#define NN   4096
#define FIN  512
#define H    4
#define F    64
#define HF   256
#define LOG2E 1.44269504088896340736f

typedef __attribute__((ext_vector_type(4))) float f32x4;
typedef __attribute__((ext_vector_type(8))) short short8;

union U8 { short8 s; unsigned int w[4]; };

// ---------------- K01: fused (GEMM+scores+transpose) | mask-pack ----------
__global__ __launch_bounds__(256) void gemm_scores_pack(
        const float* __restrict__ X, const float* __restrict__ W,
        const float* __restrict__ a_src, const float* __restrict__ a_dst,
        const int* __restrict__ A,
        float* __restrict__ f1h, float* __restrict__ f2h,
        unsigned short* __restrict__ Vhi,
        unsigned long long* __restrict__ Ab) {
    if (blockIdx.x >= 512) {
        const int pb   = blockIdx.x - 512;                    // 0..1023
        const int gw   = (pb * 256 + threadIdx.x) >> 6;
        const int lane = threadIdx.x & 63;
        const int nchunk = NN * NN / 64;                      // 262144
        for (int c = gw; c < nchunk; c += 4096) {
            int a = A[(size_t)c * 64 + lane];
            unsigned long long m = __ballot(a != 0);
            if (lane == 0) Ab[c] = m;
        }
        return;
    }

    __shared__ float Ast[32][34];            // [k][m]
    __shared__ float Bs[32][64];             // [k][n]
    __shared__ unsigned short Vt[64][40];    // [f][n]

    const int bi = blockIdx.x & 127, h = blockIdx.x >> 7;
    const int t  = threadIdx.x;
    const int tx = t & 15, ty = t >> 4;

    float acc[2][4];
#pragma unroll
    for (int r = 0; r < 2; ++r)
#pragma unroll
        for (int c = 0; c < 4; ++c) acc[r][c] = 0.f;

    const int ar = t >> 3, ak = (t & 7) * 4;
    const int bk = t >> 3, bn = (t & 7) * 8;

    const float* Ap = X + (size_t)(bi * 32 + ar) * FIN + ak;
    const float* Bp = W + (size_t)bk * HF + h * F + bn;

    for (int k0 = 0; k0 < FIN; k0 += 32) {
        float4 av  = *(const float4*)(Ap + k0);
        float4 bv0 = *(const float4*)(Bp + (size_t)k0 * HF);
        float4 bv1 = *(const float4*)(Bp + (size_t)k0 * HF + 4);
        __syncthreads();
        Ast[ak + 0][ar] = av.x;
        Ast[ak + 1][ar] = av.y;
        Ast[ak + 2][ar] = av.z;
        Ast[ak + 3][ar] = av.w;
        *(float4*)&Bs[bk][bn] = bv0;
        *(float4*)&Bs[bk][bn + 4] = bv1;
        __syncthreads();
#pragma unroll
        for (int kk = 0; kk < 32; ++kk) {
            float2 a2 = *(const float2*)&Ast[kk][ty * 2];
            float4 b4 = *(const float4*)&Bs[kk][tx * 4];
            acc[0][0] += a2.x * b4.x; acc[0][1] += a2.x * b4.y;
            acc[0][2] += a2.x * b4.z; acc[0][3] += a2.x * b4.w;
            acc[1][0] += a2.y * b4.x; acc[1][1] += a2.y * b4.y;
            acc[1][2] += a2.y * b4.z; acc[1][3] += a2.y * b4.w;
        }
    }

    float4 as4 = *(const float4*)(a_src + h * F + tx * 4);
    float4 ad4 = *(const float4*)(a_dst + h * F + tx * 4);
#pragma unroll
    for (int r = 0; r < 2; ++r) {
        float s1 = acc[r][0] * as4.x + acc[r][1] * as4.y
                 + acc[r][2] * as4.z + acc[r][3] * as4.w;
        float s2 = acc[r][0] * ad4.x + acc[r][1] * ad4.y
                 + acc[r][2] * ad4.z + acc[r][3] * ad4.w;
#pragma unroll
        for (int off = 1; off < 16; off <<= 1) {
            s1 += __shfl_xor(s1, off, 16);
            s2 += __shfl_xor(s2, off, 16);
        }
        if (tx == 0) {
            const int n = bi * 32 + ty * 2 + r;
            f1h[h * NN + n] = s1 * LOG2E;
            f2h[h * NN + n] = s2 * LOG2E;
        }
    }

    __syncthreads();
#pragma unroll
    for (int r = 0; r < 2; ++r)
#pragma unroll
        for (int c = 0; c < 4; ++c) {
            __hip_bfloat16 b = __float2bfloat16(acc[r][c]);
            Vt[tx * 4 + c][ty * 2 + r] = __builtin_bit_cast(unsigned short, b);
        }
    __syncthreads();
    {
        const int f = t >> 2, ch = t & 3;
        short8 v = *(const short8*)&Vt[f][ch * 8];
        *(short8*)&Vhi[(size_t)(h * F + f) * NN + bi * 32 + ch * 8] = v;
    }
}

// ---------------- K3: MFMA fused attention (partials) ----------------
// grid (128, njb): ib = 32-row block, jb = JLEN-col strip. wave = head.
template <int JLEN>
__global__ __launch_bounds__(256) void gat_attn_mfma(
        const unsigned int* __restrict__ Ab32,
        const unsigned short* __restrict__ Vhi,
        const float* __restrict__ f1h, const float* __restrict__ f2h,
        float* __restrict__ pacc, float* __restrict__ plsum) {
    constexpr int NCC = JLEN / 32;
    const int ib = blockIdx.x, jb = blockIdx.y;
    const int h    = threadIdx.x >> 6;
    const int lane = threadIdx.x & 63;
    const int il = lane & 15;        // MFMA A row / B,C/D col
    const int kg = lane >> 4;        // k-group
    const int sh = kg * 8;
    const int i0 = ib * 32 + il;
    const int i1 = i0 + 16;

    const float c0 = f1h[h * NN + i0];
    const float c1 = f1h[h * NN + i1];

    const unsigned int* ab0 = Ab32 + (size_t)i0 * (NN / 32) + jb * (JLEN / 32);
    const unsigned int* ab1 = Ab32 + (size_t)i1 * (NN / 32) + jb * (JLEN / 32);
    const float* f2b = f2h + (size_t)h * NN + jb * JLEN + sh;

    // hoisted per-ft V strip bases (in-loop offset = cc*32 elems = 64B)
    const unsigned short* vb0 = Vhi + (size_t)(h * F + 0  + il) * NN + jb * JLEN + sh;
    const unsigned short* vb1 = Vhi + (size_t)(h * F + 16 + il) * NN + jb * JLEN + sh;
    const unsigned short* vb2 = Vhi + (size_t)(h * F + 32 + il) * NN + jb * JLEN + sh;
    const unsigned short* vb3 = Vhi + (size_t)(h * F + 48 + il) * NN + jb * JLEN + sh;

    f32x4 acc0[4], acc1[4], lac0, lac1;
#pragma unroll
    for (int ft = 0; ft < 4; ++ft) {
        acc0[ft] = (f32x4){0.f, 0.f, 0.f, 0.f};
        acc1[ft] = (f32x4){0.f, 0.f, 0.f, 0.f};
    }
    lac0 = (f32x4){0.f, 0.f, 0.f, 0.f};
    lac1 = (f32x4){0.f, 0.f, 0.f, 0.f};

    short8 ones;
#pragma unroll
    for (int e = 0; e < 8; ++e) ones[e] = (short)0x3F80;   // bf16 1.0

#pragma unroll 4
    for (int cc = 0; cc < NCC; ++cc) {
        const unsigned int m0 = ab0[cc] >> sh;   // L1/L2 broadcast
        const unsigned int m1 = ab1[cc] >> sh;

        float4 ga = *(const float4*)(f2b + cc * 32);
        float4 gb = *(const float4*)(f2b + cc * 32 + 4);
        float gv[8] = {ga.x, ga.y, ga.z, ga.w, gb.x, gb.y, gb.z, gb.w};

        float p0[8], p1[8];
#pragma unroll
        for (int e = 0; e < 8; ++e) {
            float s0 = c0 + gv[e];
            s0 = fmaxf(s0, 0.2f * s0);                  // leaky relu
            float q0 = __builtin_amdgcn_exp2f(s0);      // raw v_exp_f32
            p0[e] = ((m0 >> e) & 1u) ? q0 : 0.f;
            float s1 = c1 + gv[e];
            s1 = fmaxf(s1, 0.2f * s1);
            float q1 = __builtin_amdgcn_exp2f(s1);
            p1[e] = ((m1 >> e) & 1u) ? q1 : 0.f;
        }

        // truncation pack: elem e = top16(p[e]); v_perm pairs 2 f32 -> 1 dword
        // (R5-validated selector: low short = top16(arg2), high = top16(arg1))
        U8 pa0, pa1;
#pragma unroll
        for (int e = 0; e < 8; e += 2) {
            pa0.w[e >> 1] = __builtin_amdgcn_perm(__float_as_uint(p0[e + 1]),
                                                  __float_as_uint(p0[e]),
                                                  0x07060302u);
            pa1.w[e >> 1] = __builtin_amdgcn_perm(__float_as_uint(p1[e + 1]),
                                                  __float_as_uint(p1[e]),
                                                  0x07060302u);
        }

        short8 bh0 = *reinterpret_cast<const short8*>(vb0 + cc * 32);
        short8 bh1 = *reinterpret_cast<const short8*>(vb1 + cc * 32);
        short8 bh2 = *reinterpret_cast<const short8*>(vb2 + cc * 32);
        short8 bh3 = *reinterpret_cast<const short8*>(vb3 + cc * 32);

        acc0[0] = __builtin_amdgcn_mfma_f32_16x16x32_bf16(pa0.s, bh0, acc0[0], 0, 0, 0);
        acc1[0] = __builtin_amdgcn_mfma_f32_16x16x32_bf16(pa1.s, bh0, acc1[0], 0, 0, 0);
        acc0[1] = __builtin_amdgcn_mfma_f32_16x16x32_bf16(pa0.s, bh1, acc0[1], 0, 0, 0);
        acc1[1] = __builtin_amdgcn_mfma_f32_16x16x32_bf16(pa1.s, bh1, acc1[1], 0, 0, 0);
        acc0[2] = __builtin_amdgcn_mfma_f32_16x16x32_bf16(pa0.s, bh2, acc0[2], 0, 0, 0);
        acc1[2] = __builtin_amdgcn_mfma_f32_16x16x32_bf16(pa1.s, bh2, acc1[2], 0, 0, 0);
        acc0[3] = __builtin_amdgcn_mfma_f32_16x16x32_bf16(pa0.s, bh3, acc0[3], 0, 0, 0);
        acc1[3] = __builtin_amdgcn_mfma_f32_16x16x32_bf16(pa1.s, bh3, acc1[3], 0, 0, 0);
        lac0 = __builtin_amdgcn_mfma_f32_16x16x32_bf16(pa0.s, ones, lac0, 0, 0, 0);
        lac1 = __builtin_amdgcn_mfma_f32_16x16x32_bf16(pa1.s, ones, lac1, 0, 0, 0);
    }

    // C/D layout: col = lane&15, row = (lane>>4)*4 + reg
    float* pb = pacc + (size_t)jb * NN * HF + (size_t)(ib * 32) * HF;
#pragma unroll
    for (int ft = 0; ft < 4; ++ft)
#pragma unroll
        for (int r = 0; r < 4; ++r) {
            pb[(kg * 4 + r) * HF + h * F + ft * 16 + il]      = acc0[ft][r];
            pb[(16 + kg * 4 + r) * HF + h * F + ft * 16 + il] = acc1[ft][r];
        }

    if (il == 0) {
#pragma unroll
        for (int r = 0; r < 4; ++r) {
            plsum[(size_t)jb * NN * H + (size_t)(ib * 32 + kg * 4 + r) * H + h]      = lac0[r];
            plsum[(size_t)jb * NN * H + (size_t)(ib * 32 + 16 + kg * 4 + r) * H + h] = lac1[r];
        }
    }
}

// ---------------- K4: combine partials, normalize, ELU (float4) ----------
__global__ __launch_bounds__(256) void finalize(
        const float* __restrict__ pacc, const float* __restrict__ plsum,
        const unsigned short* __restrict__ Vhi, float* __restrict__ out,
        int njb) {
    const int gid4 = blockIdx.x * 256 + threadIdx.x;   // 0 .. NN*HF/4-1
    const int i = gid4 >> 6, q = gid4 & 63;
    const int h = q >> 4;
    float4 a = make_float4(0.f, 0.f, 0.f, 0.f);
    float l = 0.f;
    for (int jb = 0; jb < njb; ++jb) {
        float4 p = *(const float4*)&pacc[(size_t)jb * NN * HF + (size_t)i * HF + q * 4];
        a.x += p.x; a.y += p.y; a.z += p.z; a.w += p.w;
        l += plsum[(size_t)jb * NN * H + (size_t)i * H + h];
    }
    float av[4] = {a.x, a.y, a.z, a.w};
    if (l == 0.f) {   // empty row: reference softmax degenerates to uniform
#pragma unroll
        for (int c = 0; c < 4; ++c) {
            const unsigned short* col = Vhi + (size_t)(q * 4 + c) * NN;
            float s = 0.f;
            for (int j = 0; j < NN; ++j)
                s += __uint_as_float(((unsigned int)col[j]) << 16);
            av[c] = s;
        }
        l = (float)NN;
    }
    const float rl = 1.0f / l;
    float4 o;
    float* op = &o.x;
#pragma unroll
    for (int c = 0; c < 4; ++c) {
        float v = av[c] * rl;
        op[c] = (v > 0.f) ? v : (__builtin_amdgcn_exp2f(v * LOG2E) - 1.f);
    }
    *(float4*)&out[(size_t)i * HF + q * 4] = o;
}

// ---------------- launch ----------------
extern "C" void kernel_launch(void* const* d_in, const int* in_sizes, int n_in,
                              void* d_out, int out_size, void* d_ws, size_t ws_size,
                              hipStream_t stream) {
    const float* X     = (const float*)d_in[0];
    const int*   A     = (const int*)d_in[1];
    const float* W     = (const float*)d_in[2];
    const float* a_src = (const float*)d_in[3];
    const float* a_dst = (const float*)d_in[4];
    float* out = (float*)d_out;

    const size_t fixed = (size_t)2 * NN * H * 4 + (size_t)HF * NN * 2
                       + (size_t)NN * NN / 8;
    auto need = [&](int njb) {
        return (size_t)njb * NN * HF * 4 + (size_t)njb * NN * H * 4 + fixed;
    };
    const int njb = (ws_size >= need(8)) ? 8 : 4;   // deterministic in ws_size

    float* pacc = (float*)d_ws;
    float* f1h  = pacc + (size_t)njb * NN * HF;
    float* f2h  = f1h + (size_t)NN * H;
    unsigned short* Vhi = (unsigned short*)(f2h + (size_t)NN * H);
    float* plsum = (float*)(Vhi + (size_t)HF * NN);
    unsigned long long* Ab = (unsigned long long*)(plsum + (size_t)njb * NN * H);

    gemm_scores_pack<<<1536, 256, 0, stream>>>(X, W, a_src, a_dst, A,
                                               f1h, f2h, Vhi, Ab);
    if (njb == 8)
        gat_attn_mfma<512><<<dim3(128, 8), 256, 0, stream>>>(
            (const unsigned int*)Ab, Vhi, f1h, f2h, pacc, plsum);
    else
        gat_attn_mfma<1024><<<dim3(128, 4), 256, 0, stream>>>(
            (const unsigned int*)Ab, Vhi, f1h, f2h, pacc, plsum);
    finalize<<<NN * HF / 4 / 256, 256, 0, stream>>>(pacc, plsum, Vhi, out, njb);
}

// Round 10
// 71.171 us; speedup vs baseline: 2.2941x; 1.1408x over previous
//
#include <hip/hip_runtime.h>
#include <hip/hip_bf16.h>

// GAT layer, N=4096, FIN=512, H=4 heads, F=64.
// R10: arithmetic-intensity attack (R9 showed VALU cuts don't move the wall;
// K3 is ~75% exposed memory latency at 23% occupancy).
//   K01: heterogeneous — blocks<256: GEMM 64x64 tile / 4x4 micro-tile
//        (16 FMA per 2 LDS reads, 2.7x intensity) + scores + bf16-V-transpose;
//        blocks>=256: grid-stride ballot mask-pack (1024 blocks; memory waves
//        complement the gemm's VALU waves).
//   K3:  64 rows/block (4 rowtiles): each V-fragment load feeds 4 rowtile
//        MFMAs -> V-load instrs halve, latency amortized 2x. 20 MFMA/cc.
//        Raw v_exp_f32, trunc-packed P (R9). No max-subtraction (scores
//        bounded -> softmax exact without it).
//   K4:  float4 combine, normalize, ELU.
// ws: pacc njb*4MB | f1h | f2h | Vhi 2MB | plsum | Ab 2MB. njb: 8 else 4.

#define NN   4096
#define FIN  512
#define H    4
#define F    64
#define HF   256
#define LOG2E 1.44269504088896340736f

typedef __attribute__((ext_vector_type(4))) float f32x4;
typedef __attribute__((ext_vector_type(8))) short short8;

union U8 { short8 s; unsigned int w[4]; };

// ---------------- K01: fused (GEMM+scores+transpose) | mask-pack ----------
// grid 1280: blocks 0..255 = gemm (bi = b&63, h = b>>6), 256..1279 = pack.
__global__ __launch_bounds__(256) void gemm_scores_pack(
        const float* __restrict__ X, const float* __restrict__ W,
        const float* __restrict__ a_src, const float* __restrict__ a_dst,
        const int* __restrict__ A,
        float* __restrict__ f1h, float* __restrict__ f2h,
        unsigned short* __restrict__ Vhi,
        unsigned long long* __restrict__ Ab) {
    if (blockIdx.x >= 256) {
        const int pb   = blockIdx.x - 256;                    // 0..1023
        const int gw   = (pb * 256 + threadIdx.x) >> 6;
        const int lane = threadIdx.x & 63;
        const int nchunk = NN * NN / 64;                      // 262144
        for (int c = gw; c < nchunk; c += 4096) {
            int a = A[(size_t)c * 64 + lane];
            unsigned long long m = __ballot(a != 0);
            if (lane == 0) Ab[c] = m;
        }
        return;
    }

    __shared__ float Xs[32][64];             // [k][m]
    __shared__ float Ws[32][64];             // [k][n]
    __shared__ unsigned short Vt[64][72];    // [f][m], pad 72 (16B-aligned)

    const int bi = blockIdx.x & 63, h = blockIdx.x >> 6;
    const int t  = threadIdx.x;
    const int tx = t & 15, ty = t >> 4;      // micro-tile: rows ty*4, cols tx*4

    float acc[4][4];
#pragma unroll
    for (int r = 0; r < 4; ++r)
#pragma unroll
        for (int c = 0; c < 4; ++c) acc[r][c] = 0.f;

    const int xr = t >> 2, xk = (t & 3) * 8;     // X stage: row, 8 k's
    const int wk = t >> 3, wn = (t & 7) * 8;     // W stage: k, 8 n's

    const float* Xp = X + (size_t)(bi * 64 + xr) * FIN + xk;
    const float* Wp = W + (size_t)wk * HF + h * F + wn;

    for (int k0 = 0; k0 < FIN; k0 += 32) {
        float4 xv0 = *(const float4*)(Xp + k0);
        float4 xv1 = *(const float4*)(Xp + k0 + 4);
        float4 wv0 = *(const float4*)(Wp + (size_t)k0 * HF);
        float4 wv1 = *(const float4*)(Wp + (size_t)k0 * HF + 4);
        __syncthreads();
        Xs[xk + 0][xr] = xv0.x; Xs[xk + 1][xr] = xv0.y;
        Xs[xk + 2][xr] = xv0.z; Xs[xk + 3][xr] = xv0.w;
        Xs[xk + 4][xr] = xv1.x; Xs[xk + 5][xr] = xv1.y;
        Xs[xk + 6][xr] = xv1.z; Xs[xk + 7][xr] = xv1.w;
        *(float4*)&Ws[wk][wn] = wv0;
        *(float4*)&Ws[wk][wn + 4] = wv1;
        __syncthreads();
#pragma unroll
        for (int kk = 0; kk < 32; ++kk) {
            float4 a4 = *(const float4*)&Xs[kk][ty * 4];
            float4 b4 = *(const float4*)&Ws[kk][tx * 4];
            float av[4] = {a4.x, a4.y, a4.z, a4.w};
            float bv[4] = {b4.x, b4.y, b4.z, b4.w};
#pragma unroll
            for (int r = 0; r < 4; ++r)
#pragma unroll
                for (int c = 0; c < 4; ++c) acc[r][c] += av[r] * bv[c];
        }
    }

    // scores: per-row dot with a_src/a_dst over this thread's 4 cols,
    // reduced across the 16 tx lanes.
    float4 as4 = *(const float4*)(a_src + h * F + tx * 4);
    float4 ad4 = *(const float4*)(a_dst + h * F + tx * 4);
    float asv[4] = {as4.x, as4.y, as4.z, as4.w};
    float adv[4] = {ad4.x, ad4.y, ad4.z, ad4.w};
#pragma unroll
    for (int r = 0; r < 4; ++r) {
        float s1 = 0.f, s2 = 0.f;
#pragma unroll
        for (int c = 0; c < 4; ++c) { s1 += acc[r][c] * asv[c]; s2 += acc[r][c] * adv[c]; }
#pragma unroll
        for (int off = 1; off < 16; off <<= 1) {
            s1 += __shfl_xor(s1, off, 16);
            s2 += __shfl_xor(s2, off, 16);
        }
        if (tx == 0) {
            const int n = bi * 64 + ty * 4 + r;
            f1h[h * NN + n] = s1 * LOG2E;
            f2h[h * NN + n] = s2 * LOG2E;
        }
    }

    // transposed bf16 V via LDS bounce
    __syncthreads();
#pragma unroll
    for (int r = 0; r < 4; ++r)
#pragma unroll
        for (int c = 0; c < 4; ++c) {
            __hip_bfloat16 b = __float2bfloat16(acc[r][c]);
            Vt[tx * 4 + c][ty * 4 + r] = __builtin_bit_cast(unsigned short, b);
        }
    __syncthreads();
    {
        const int f = t >> 2, ch = t & 3;    // 64 f-rows x 4 chunks of 16
        short8 v0 = *(const short8*)&Vt[f][ch * 16];
        short8 v1 = *(const short8*)&Vt[f][ch * 16 + 8];
        unsigned short* dst = Vhi + (size_t)(h * F + f) * NN + bi * 64 + ch * 16;
        *(short8*)dst = v0;
        *(short8*)(dst + 8) = v1;
    }
}

// ---------------- K3: MFMA fused attention (partials) ----------------
// grid (64, njb): ib = 64-row block (4 rowtiles), jb = JLEN strip. wave=head.
template <int JLEN>
__global__ __launch_bounds__(256) void gat_attn_mfma(
        const unsigned int* __restrict__ Ab32,
        const unsigned short* __restrict__ Vhi,
        const float* __restrict__ f1h, const float* __restrict__ f2h,
        float* __restrict__ pacc, float* __restrict__ plsum) {
    constexpr int NCC = JLEN / 32;
    const int ib = blockIdx.x, jb = blockIdx.y;
    const int h    = threadIdx.x >> 6;
    const int lane = threadIdx.x & 63;
    const int il = lane & 15;        // MFMA A row / B,C/D col
    const int kg = lane >> 4;        // k-group
    const int sh = kg * 8;
    const int ibase = ib * 64 + il;

    float c[4];
#pragma unroll
    for (int rt = 0; rt < 4; ++rt) c[rt] = f1h[h * NN + ibase + rt * 16];

    const unsigned int* abp[4];
#pragma unroll
    for (int rt = 0; rt < 4; ++rt)
        abp[rt] = Ab32 + (size_t)(ibase + rt * 16) * (NN / 32) + jb * (JLEN / 32);

    const float* f2b = f2h + (size_t)h * NN + jb * JLEN + sh;

    const unsigned short* vb[4];
#pragma unroll
    for (int ft = 0; ft < 4; ++ft)
        vb[ft] = Vhi + (size_t)(h * F + ft * 16 + il) * NN + jb * JLEN + sh;

    f32x4 acc[4][4], lac[4];
#pragma unroll
    for (int rt = 0; rt < 4; ++rt) {
        lac[rt] = (f32x4){0.f, 0.f, 0.f, 0.f};
#pragma unroll
        for (int ft = 0; ft < 4; ++ft) acc[rt][ft] = (f32x4){0.f, 0.f, 0.f, 0.f};
    }

    short8 ones;
#pragma unroll
    for (int e = 0; e < 8; ++e) ones[e] = (short)0x3F80;   // bf16 1.0

#pragma unroll 2
    for (int cc = 0; cc < NCC; ++cc) {
        unsigned int m[4];
#pragma unroll
        for (int rt = 0; rt < 4; ++rt) m[rt] = abp[rt][cc] >> sh;

        float4 ga = *(const float4*)(f2b + cc * 32);
        float4 gb = *(const float4*)(f2b + cc * 32 + 4);
        float gv[8] = {ga.x, ga.y, ga.z, ga.w, gb.x, gb.y, gb.z, gb.w};

        short8 bh[4];
#pragma unroll
        for (int ft = 0; ft < 4; ++ft)
            bh[ft] = *reinterpret_cast<const short8*>(vb[ft] + cc * 32);

#pragma unroll
        for (int rt = 0; rt < 4; ++rt) {
            float pf[8];
#pragma unroll
            for (int e = 0; e < 8; ++e) {
                float s = c[rt] + gv[e];
                s = fmaxf(s, 0.2f * s);                 // leaky relu
                float q = __builtin_amdgcn_exp2f(s);    // raw v_exp_f32
                pf[e] = ((m[rt] >> e) & 1u) ? q : 0.f;
            }
            U8 pa;
#pragma unroll
            for (int e = 0; e < 8; e += 2)
                pa.w[e >> 1] = __builtin_amdgcn_perm(__float_as_uint(pf[e + 1]),
                                                     __float_as_uint(pf[e]),
                                                     0x07060302u);
#pragma unroll
            for (int ft = 0; ft < 4; ++ft)
                acc[rt][ft] = __builtin_amdgcn_mfma_f32_16x16x32_bf16(
                    pa.s, bh[ft], acc[rt][ft], 0, 0, 0);
            lac[rt] = __builtin_amdgcn_mfma_f32_16x16x32_bf16(
                pa.s, ones, lac[rt], 0, 0, 0);
        }
    }

    // C/D layout: col = lane&15, row = (lane>>4)*4 + reg
    float* pb = pacc + (size_t)jb * NN * HF + (size_t)(ib * 64) * HF;
#pragma unroll
    for (int rt = 0; rt < 4; ++rt)
#pragma unroll
        for (int ft = 0; ft < 4; ++ft)
#pragma unroll
            for (int r = 0; r < 4; ++r)
                pb[(rt * 16 + kg * 4 + r) * HF + h * F + ft * 16 + il] = acc[rt][ft][r];

    if (il == 0) {   // ones-MFMA: every col holds the row sum; use col 0
#pragma unroll
        for (int rt = 0; rt < 4; ++rt)
#pragma unroll
            for (int r = 0; r < 4; ++r)
                plsum[(size_t)jb * NN * H
                      + (size_t)(ib * 64 + rt * 16 + kg * 4 + r) * H + h] = lac[rt][r];
    }
}

// ---------------- K4: combine partials, normalize, ELU (float4) ----------
__global__ __launch_bounds__(256) void finalize(
        const float* __restrict__ pacc, const float* __restrict__ plsum,
        const unsigned short* __restrict__ Vhi, float* __restrict__ out,
        int njb) {
    const int gid4 = blockIdx.x * 256 + threadIdx.x;   // 0 .. NN*HF/4-1
    const int i = gid4 >> 6, q = gid4 & 63;
    const int h = q >> 4;
    float4 a = make_float4(0.f, 0.f, 0.f, 0.f);
    float l = 0.f;
    for (int jb = 0; jb < njb; ++jb) {
        float4 p = *(const float4*)&pacc[(size_t)jb * NN * HF + (size_t)i * HF + q * 4];
        a.x += p.x; a.y += p.y; a.z += p.z; a.w += p.w;
        l += plsum[(size_t)jb * NN * H + (size_t)i * H + h];
    }
    float av[4] = {a.x, a.y, a.z, a.w};
    if (l == 0.f) {   // empty row: reference softmax degenerates to uniform
#pragma unroll
        for (int c = 0; c < 4; ++c) {
            const unsigned short* col = Vhi + (size_t)(q * 4 + c) * NN;
            float s = 0.f;
            for (int j = 0; j < NN; ++j)
                s += __uint_as_float(((unsigned int)col[j]) << 16);
            av[c] = s;
        }
        l = (float)NN;
    }
    const float rl = 1.0f / l;
    float4 o;
    float* op = &o.x;
#pragma unroll
    for (int c = 0; c < 4; ++c) {
        float v = av[c] * rl;
        op[c] = (v > 0.f) ? v : (__builtin_amdgcn_exp2f(v * LOG2E) - 1.f);
    }
    *(float4*)&out[(size_t)i * HF + q * 4] = o;
}

// ---------------- launch ----------------
extern "C" void kernel_launch(void* const* d_in, const int* in_sizes, int n_in,
                              void* d_out, int out_size, void* d_ws, size_t ws_size,
                              hipStream_t stream) {
    const float* X     = (const float*)d_in[0];
    const int*   A     = (const int*)d_in[1];
    const float* W     = (const float*)d_in[2];
    const float* a_src = (const float*)d_in[3];
    const float* a_dst = (const float*)d_in[4];
    float* out = (float*)d_out;

    const size_t fixed = (size_t)2 * NN * H * 4 + (size_t)HF * NN * 2
                       + (size_t)NN * NN / 8;
    auto need = [&](int njb) {
        return (size_t)njb * NN * HF * 4 + (size_t)njb * NN * H * 4 + fixed;
    };
    const int njb = (ws_size >= need(8)) ? 8 : 4;   // deterministic in ws_size

    float* pacc = (float*)d_ws;
    float* f1h  = pacc + (size_t)njb * NN * HF;
    float* f2h  = f1h + (size_t)NN * H;
    unsigned short* Vhi = (unsigned short*)(f2h + (size_t)NN * H);
    float* plsum = (float*)(Vhi + (size_t)HF * NN);
    unsigned long long* Ab = (unsigned long long*)(plsum + (size_t)njb * NN * H);

    gemm_scores_pack<<<1280, 256, 0, stream>>>(X, W, a_src, a_dst, A,
                                               f1h, f2h, Vhi, Ab);
    if (njb == 8)
        gat_attn_mfma<512><<<dim3(64, 8), 256, 0, stream>>>(
            (const unsigned int*)Ab, Vhi, f1h, f2h, pacc, plsum);
    else
        gat_attn_mfma<1024><<<dim3(64, 4), 256, 0, stream>>>(
            (const unsigned int*)Ab, Vhi, f1h, f2h, pacc, plsum);
    finalize<<<NN * HF / 4 / 256, 256, 0, stream>>>(pacc, plsum, Vhi, out, njb);
}